// Round 1
// 2117.842 us; speedup vs baseline: 1.1478x; 1.1478x over previous
//
#include <hip/hip_runtime.h>

// ---------------------------------------------------------------------------
// T5 backbone forward, round 4:
//  - GEMM K-loop rebuilt as double-buffered prefetch pipeline (T3 minimum
//    2-phase: STAGE(next) issued BEFORE compute(cur), single barrier/iter)
//  - LDS XOR chunk-swizzle on A/B tiles: pre-swizzled global_load_lds source
//    + swizzled ds_read chunk (both-sides involution, rule 21) to kill the
//    16-lane/4-bank ds_read_b128 conflicts (9.4M conflict-cycles/dispatch)
//  - same swizzle on flash-attn Qs/Ks tiles (manual staging -> swizzle dest)
//  - cross-attn QKV projections merged into ONE launch (dual-A qkv GEMM)
// ---------------------------------------------------------------------------

#define LNUM 6
#define HDIM 1024
#define NHEAD 16
#define DHEAD 64
#define BDIM 4
#define SDIM 512
#define FDIM 4096
#define MROWS (BDIM * SDIM)   // 2048

typedef __bf16 bf16_t;
typedef bf16_t bf16x8 __attribute__((ext_vector_type(8)));
typedef float f32x4 __attribute__((ext_vector_type(4)));

__device__ __forceinline__ float bf2f(unsigned short u) {
    union { unsigned int i; float f; } x;
    x.i = ((unsigned int)u) << 16;
    return x.f;
}

__device__ __forceinline__ unsigned short f2bf(float f) {
    union { float f; unsigned int i; } u;
    u.f = f;
    unsigned int x = u.i;
    unsigned int lsb = (x >> 16) & 1u;
    x += 0x7fffu + lsb;           // round-to-nearest-even
    return (unsigned short)(x >> 16);
}

// async global->LDS, 16 bytes per lane; lds dest = wave-uniform base + lane*16
__device__ __forceinline__ void async16(const unsigned short* g, unsigned short* l) {
    __builtin_amdgcn_global_load_lds(
        (const __attribute__((address_space(1))) unsigned int*)g,
        (__attribute__((address_space(3))) unsigned int*)l, 16, 0, 0);
}

// ---------------------------------------------------------------------------
// MFMA GEMM: C[M,N] = A[M,K](bf16) @ BT[N,K](bf16)^T + bias(f32)
// BM=128, BK=64, 256 threads (4 waves as 2x2), per-wave 64 x BN/2 output.
// Double-buffered LDS prefetch; XOR chunk-swizzled tiles.
// ---------------------------------------------------------------------------
template<int BN, bool GELU, bool OUTBF16>
__global__ __launch_bounds__(256) void mfma_gemm(
    const unsigned short* __restrict__ A,
    const unsigned short* __restrict__ BT,
    const float* __restrict__ bias,
    void* __restrict__ Cv,
    int M, int N, int K)
{
    constexpr int BM = 128;
    constexpr int BK = 64;
    constexpr int MI = 4;
    constexpr int NJ = BN / 32;

    __shared__ unsigned short As[2][BM][BK];
    __shared__ unsigned short Bs[2][BN][BK];

    const int t = threadIdx.x;
    const int w = t >> 6;
    const int lane = t & 63;
    const int quad = lane >> 4;
    const int cm = lane & 15;
    const int wrow = (w >> 1) * 64;
    const int wcol = (w & 1) * (BN / 2);
    const int row0 = blockIdx.x * BM;
    const int col0 = blockIdx.y * BN;

    f32x4 acc[MI][NJ] = {};

    const int lrow = lane >> 3;
    // pre-swizzled source chunk: physical LDS chunk (lane&7) of row lrow gets
    // logical chunk (lane&7)^lrow  =>  read side XORs by (row&7) to recover
    const int lcol = ((lane & 7) ^ lrow) * 8;
    const int sw = cm & 7;

    auto stage = [&](int buf, int k0) {
#pragma unroll
        for (int j = 0; j < 4; ++j) {
            int mb = w * 32 + j * 8;
            async16(A + (size_t)(row0 + mb + lrow) * K + k0 + lcol, &As[buf][mb][0]);
        }
#pragma unroll
        for (int j = 0; j < NJ; ++j) {
            int nb = w * (BN / 4) + j * 8;
            async16(BT + (size_t)(col0 + nb + lrow) * K + k0 + lcol, &Bs[buf][nb][0]);
        }
    };

    stage(0, 0);
    __syncthreads();   // compiler emits vmcnt(0) drain before barrier

    int cur = 0;
    for (int k0 = 0; k0 < K; k0 += BK) {
        if (k0 + BK < K) stage(cur ^ 1, k0 + BK);   // prefetch next tile

#pragma unroll
        for (int kk = 0; kk < BK; kk += 32) {
            const int cc = kk >> 3;                  // logical chunk base (0 or 4)
            bf16x8 av[MI], bv[NJ];
#pragma unroll
            for (int i = 0; i < MI; ++i)
                av[i] = *(const bf16x8*)&As[cur][wrow + 16 * i + cm][((cc + quad) ^ sw) * 8];
#pragma unroll
            for (int j = 0; j < NJ; ++j)
                bv[j] = *(const bf16x8*)&Bs[cur][wcol + 16 * j + cm][((cc + quad) ^ sw) * 8];
#pragma unroll
            for (int i = 0; i < MI; ++i)
#pragma unroll
                for (int j = 0; j < NJ; ++j)
                    acc[i][j] = __builtin_amdgcn_mfma_f32_16x16x32_bf16(
                        av[i], bv[j], acc[i][j], 0, 0, 0);
        }
        __syncthreads();   // drains prefetch vmcnt + guards buffer reuse
        cur ^= 1;
    }

#pragma unroll
    for (int j = 0; j < NJ; ++j) {
        int col = col0 + wcol + 16 * j + cm;
        float bb = bias[col];
#pragma unroll
        for (int i = 0; i < MI; ++i) {
#pragma unroll
            for (int r = 0; r < 4; ++r) {
                int row = row0 + wrow + 16 * i + quad * 4 + r;
                float c = acc[i][j][r] + bb;
                if (GELU) {
                    float u = 0.7978845608028654f * (c + 0.044715f * c * c * c);
                    c = 0.5f * c * (1.0f + tanhf(u));
                }
                if (OUTBF16)
                    ((unsigned short*)Cv)[(size_t)row * N + col] = f2bf(c);
                else
                    ((float*)Cv)[(size_t)row * N + col] = c;
            }
        }
    }
}

// ---------------------------------------------------------------------------
// Fused QKV GEMM with dual A: col block 0 (Q) reads Aq, blocks 1/2 (K,V) read
// Akv. BT[3072,K]^T + bias[3072] -> q/k/v bf16 [M][1024].
// Same pipeline + swizzle as mfma_gemm.
// ---------------------------------------------------------------------------
__global__ __launch_bounds__(256) void mfma_gemm_qkv(
    const unsigned short* __restrict__ Aq,
    const unsigned short* __restrict__ Akv,
    const unsigned short* __restrict__ BT,
    const float* __restrict__ bias,
    unsigned short* __restrict__ qo,
    unsigned short* __restrict__ ko,
    unsigned short* __restrict__ vo,
    int M, int K)
{
    constexpr int BM = 128;
    constexpr int BK = 64;
    constexpr int BN = 64;
    constexpr int MI = 4;
    constexpr int NJ = 2;

    __shared__ unsigned short As[2][BM][BK];
    __shared__ unsigned short Bs[2][BN][BK];

    const int t = threadIdx.x;
    const int w = t >> 6;
    const int lane = t & 63;
    const int quad = lane >> 4;
    const int cm = lane & 15;
    const int wrow = (w >> 1) * 64;
    const int wcol = (w & 1) * 32;
    const int row0 = blockIdx.x * BM;
    const int col0 = blockIdx.y * BN;      // 0..3071

    const int which = col0 >> 10;
    const unsigned short* __restrict__ A = (which == 0) ? Aq : Akv;

    f32x4 acc[MI][NJ] = {};

    const int lrow = lane >> 3;
    const int lcol = ((lane & 7) ^ lrow) * 8;
    const int sw = cm & 7;

    auto stage = [&](int buf, int k0) {
#pragma unroll
        for (int j = 0; j < 4; ++j) {
            int mb = w * 32 + j * 8;
            async16(A + (size_t)(row0 + mb + lrow) * K + k0 + lcol, &As[buf][mb][0]);
        }
#pragma unroll
        for (int j = 0; j < NJ; ++j) {
            int nb = w * 16 + j * 8;
            async16(BT + (size_t)(col0 + nb + lrow) * K + k0 + lcol, &Bs[buf][nb][0]);
        }
    };

    stage(0, 0);
    __syncthreads();

    int cur = 0;
    for (int k0 = 0; k0 < K; k0 += BK) {
        if (k0 + BK < K) stage(cur ^ 1, k0 + BK);

#pragma unroll
        for (int kk = 0; kk < BK; kk += 32) {
            const int cc = kk >> 3;
            bf16x8 av[MI], bv[NJ];
#pragma unroll
            for (int i = 0; i < MI; ++i)
                av[i] = *(const bf16x8*)&As[cur][wrow + 16 * i + cm][((cc + quad) ^ sw) * 8];
#pragma unroll
            for (int j = 0; j < NJ; ++j)
                bv[j] = *(const bf16x8*)&Bs[cur][wcol + 16 * j + cm][((cc + quad) ^ sw) * 8];
#pragma unroll
            for (int i = 0; i < MI; ++i)
#pragma unroll
                for (int j = 0; j < NJ; ++j)
                    acc[i][j] = __builtin_amdgcn_mfma_f32_16x16x32_bf16(
                        av[i], bv[j], acc[i][j], 0, 0, 0);
        }
        __syncthreads();
        cur ^= 1;
    }

    unsigned short* dst = (which == 0) ? qo : (which == 1) ? ko : vo;
    const int cbase = col0 & 1023;

#pragma unroll
    for (int j = 0; j < NJ; ++j) {
        int col = col0 + wcol + 16 * j + cm;
        float bb = bias[col];
        int coll = cbase + wcol + 16 * j + cm;
#pragma unroll
        for (int i = 0; i < MI; ++i) {
#pragma unroll
            for (int r = 0; r < 4; ++r) {
                int row = row0 + wrow + 16 * i + quad * 4 + r;
                dst[(size_t)row * HDIM + coll] = f2bf(acc[i][j][r] + bb);
            }
        }
    }
}

// ---------------------------------------------------------------------------
// Flash attention: grid (S/64, NH, B), 256 threads (4 waves).
// Each wave owns 16 q-rows; KV tiles of 64; online softmax; ctx bf16 out.
// Qs/Ks XOR chunk-swizzled (manual staging -> swizzle the store address).
// ---------------------------------------------------------------------------
__global__ __launch_bounds__(256) void flash_attn(
    const unsigned short* __restrict__ q,
    const unsigned short* __restrict__ k,
    const unsigned short* __restrict__ v,
    const int* __restrict__ mask,
    unsigned short* __restrict__ ctx)
{
    __shared__ unsigned short Qs[64][64];
    __shared__ unsigned short Ks[64][64];
    __shared__ unsigned short Vs[64][72];      // transposed: Vs[d][j] (padded)
    __shared__ unsigned short Ps[4][16][72];   // per-wave P tile [m][j] (padded)

    const int t = threadIdx.x;
    const int w = t >> 6;
    const int lane = t & 63;
    const int quad = lane >> 4;
    const int cm = lane & 15;
    const int sw = cm & 7;

    const int q0 = blockIdx.x * 64;
    const int h = blockIdx.y;
    const int b = blockIdx.z;
    const size_t rowbase = (size_t)b * SDIM;
    const int hoff = h * DHEAD;

    // stage Q tile (64x64), swizzled chunks
#pragma unroll
    for (int l = 0; l < 2; ++l) {
        int idx = t + l * 256;           // 0..511
        int r = idx >> 3;                // 0..63
        int c = idx & 7;                 // logical chunk
        *(uint4*)&Qs[r][((c ^ (r & 7)) * 8)] =
            *(const uint4*)(q + (rowbase + q0 + r) * HDIM + hoff + c * 8);
    }

    float m_prev[4] = {-1e30f, -1e30f, -1e30f, -1e30f};
    float l_sum[4] = {0.0f, 0.0f, 0.0f, 0.0f};
    f32x4 oacc[4] = {};

    for (int j0 = 0; j0 < SDIM; j0 += 64) {
        __syncthreads();   // previous iteration's compute done before restaging
        // stage K tile (64x64, swizzled) and V tile transposed
#pragma unroll
        for (int l = 0; l < 2; ++l) {
            int idx = t + l * 256;
            int r = idx >> 3;
            int c = idx & 7;
            *(uint4*)&Ks[r][((c ^ (r & 7)) * 8)] =
                *(const uint4*)(k + (rowbase + j0 + r) * HDIM + hoff + c * 8);
        }
#pragma unroll
        for (int l = 0; l < 4; ++l) {
            int idx = t + l * 256;       // 0..1023
            int jj = idx >> 4;           // 0..63
            int d0 = (idx & 15) * 4;
            ushort4 vv = *(const ushort4*)(v + (rowbase + j0 + jj) * HDIM + hoff + d0);
            Vs[d0 + 0][jj] = vv.x;
            Vs[d0 + 1][jj] = vv.y;
            Vs[d0 + 2][jj] = vv.z;
            Vs[d0 + 3][jj] = vv.w;
        }
        __syncthreads();

        // S = Q K^T for this wave's 16 rows x 64 kv cols
        f32x4 sacc[4] = {};
#pragma unroll
        for (int kk = 0; kk < 64; kk += 32) {
            const int cc = kk >> 3;
            bf16x8 av = *(const bf16x8*)&Qs[w * 16 + cm][((cc + quad) ^ sw) * 8];
#pragma unroll
            for (int j2 = 0; j2 < 4; ++j2) {
                bf16x8 bv = *(const bf16x8*)&Ks[j2 * 16 + cm][((cc + quad) ^ sw) * 8];
                sacc[j2] = __builtin_amdgcn_mfma_f32_16x16x32_bf16(av, bv, sacc[j2], 0, 0, 0);
            }
        }

        // mask adders for this lane's 4 columns
        float madd[4];
#pragma unroll
        for (int j2 = 0; j2 < 4; ++j2)
            madd[j2] = (1.0f - (float)mask[b * SDIM + j0 + j2 * 16 + cm]) * -10000.0f;

        // online softmax per row r (rows quad*4+r of the wave's 16)
#pragma unroll
        for (int r = 0; r < 4; ++r) {
            float s0 = sacc[0][r] * 0.125f + madd[0];
            float s1 = sacc[1][r] * 0.125f + madd[1];
            float s2 = sacc[2][r] * 0.125f + madd[2];
            float s3 = sacc[3][r] * 0.125f + madd[3];
            float rm = fmaxf(fmaxf(s0, s1), fmaxf(s2, s3));
#pragma unroll
            for (int mo = 1; mo < 16; mo <<= 1)
                rm = fmaxf(rm, __shfl_xor(rm, mo, 64));
            float new_m = fmaxf(m_prev[r], rm);
            float alpha = __expf(m_prev[r] - new_m);
            m_prev[r] = new_m;
            float p0 = __expf(s0 - new_m);
            float p1 = __expf(s1 - new_m);
            float p2 = __expf(s2 - new_m);
            float p3 = __expf(s3 - new_m);
            float rs = p0 + p1 + p2 + p3;
#pragma unroll
            for (int mo = 1; mo < 16; mo <<= 1)
                rs += __shfl_xor(rs, mo, 64);
            l_sum[r] = l_sum[r] * alpha + rs;
#pragma unroll
            for (int d2 = 0; d2 < 4; ++d2)
                oacc[d2][r] *= alpha;
            int prow = quad * 4 + r;
            Ps[w][prow][0 * 16 + cm] = f2bf(p0);
            Ps[w][prow][1 * 16 + cm] = f2bf(p1);
            Ps[w][prow][2 * 16 + cm] = f2bf(p2);
            Ps[w][prow][3 * 16 + cm] = f2bf(p3);
        }
        // wave-synchronous: own wave's Ps writes visible after lgkmcnt (compiler)

        // O += P V
#pragma unroll
        for (int kk = 0; kk < 64; kk += 32) {
            bf16x8 pa = *(const bf16x8*)&Ps[w][cm][kk + quad * 8];
#pragma unroll
            for (int d2 = 0; d2 < 4; ++d2) {
                bf16x8 bv = *(const bf16x8*)&Vs[d2 * 16 + cm][kk + quad * 8];
                oacc[d2] = __builtin_amdgcn_mfma_f32_16x16x32_bf16(pa, bv, oacc[d2], 0, 0, 0);
            }
        }
    }

    // epilogue: divide by l, write ctx
#pragma unroll
    for (int r = 0; r < 4; ++r) {
        float inv = 1.0f / l_sum[r];
        int row = q0 + w * 16 + quad * 4 + r;
#pragma unroll
        for (int d2 = 0; d2 < 4; ++d2) {
            ctx[(rowbase + row) * HDIM + hoff + d2 * 16 + cm] = f2bf(oacc[d2][r] * inv);
        }
    }
}

// ---------------------------------------------------------------------------
// Weight convert + transpose: fp32 [K][N] -> bf16 [N][K]. 64x64 tiles.
// ---------------------------------------------------------------------------
__global__ __launch_bounds__(256) void convtrans_kernel(
    const float* __restrict__ in, unsigned short* __restrict__ out, int K, int N)
{
    __shared__ unsigned short tile[64][72];
    const size_t moff = (size_t)blockIdx.z * K * N;
    const int n0 = blockIdx.x * 64, k0 = blockIdx.y * 64;
    const int t = threadIdx.x;
#pragma unroll
    for (int l = 0; l < 4; ++l) {
        int idx = t + l * 256;
        int kk = idx >> 4;
        int nn = (idx & 15) * 4;
        float4 v = *(const float4*)(in + moff + (size_t)(k0 + kk) * N + n0 + nn);
        tile[nn + 0][kk] = f2bf(v.x);
        tile[nn + 1][kk] = f2bf(v.y);
        tile[nn + 2][kk] = f2bf(v.z);
        tile[nn + 3][kk] = f2bf(v.w);
    }
    __syncthreads();
#pragma unroll
    for (int l = 0; l < 2; ++l) {
        int c = t + l * 256;
        int nn = c >> 3;
        int kk = (c & 7) * 8;
        *(uint4*)(out + moff + (size_t)(n0 + nn) * K + k0 + kk) =
            *(const uint4*)&tile[nn][kk];
    }
}

// ---------------------------------------------------------------------------
// Fused residual + LayerNorm: out = LN(x(f32) + resid(bf16)) * g + b
// ---------------------------------------------------------------------------
template<bool OUTF32>
__global__ __launch_bounds__(256) void ln_kernel(
    const float* __restrict__ x, const unsigned short* __restrict__ resid,
    const float* __restrict__ ln, void* __restrict__ out)
{
    const int row = blockIdx.x;
    const float* xr = x + (size_t)row * HDIM;
    const unsigned short* rr = resid + (size_t)row * HDIM;
    const int t = threadIdx.x;
    __shared__ float red[4];

    float z[4];
    float s = 0.0f;
#pragma unroll
    for (int i = 0; i < 4; ++i) {
        int c = t + i * 256;
        z[i] = xr[c] + bf2f(rr[c]);
        s += z[i];
    }
#pragma unroll
    for (int off = 32; off > 0; off >>= 1) s += __shfl_down(s, off, 64);
    if ((t & 63) == 0) red[t >> 6] = s;
    __syncthreads();
    s = red[0] + red[1] + red[2] + red[3];
    float mean = s * (1.0f / (float)HDIM);

    float vs = 0.0f;
#pragma unroll
    for (int i = 0; i < 4; ++i) {
        float d = z[i] - mean;
        vs += d * d;
    }
#pragma unroll
    for (int off = 32; off > 0; off >>= 1) vs += __shfl_down(vs, off, 64);
    __syncthreads();
    if ((t & 63) == 0) red[t >> 6] = vs;
    __syncthreads();
    vs = red[0] + red[1] + red[2] + red[3];
    float inv = rsqrtf(vs * (1.0f / (float)HDIM) + 1e-12f);

#pragma unroll
    for (int i = 0; i < 4; ++i) {
        int c = t + i * 256;
        float o = (z[i] - mean) * inv * ln[c] + ln[HDIM + c];
        if (OUTF32)
            ((float*)out)[(size_t)row * HDIM + c] = o;
        else
            ((unsigned short*)out)[(size_t)row * HDIM + c] = f2bf(o);
    }
}

__global__ __launch_bounds__(256) void cvt_bf16_kernel(
    const float* __restrict__ in, unsigned short* __restrict__ out, int n4)
{
    int i = blockIdx.x * 256 + threadIdx.x;
    if (i < n4) {
        float4 v = ((const float4*)in)[i];
        ushort4 o;
        o.x = f2bf(v.x); o.y = f2bf(v.y); o.z = f2bf(v.z); o.w = f2bf(v.w);
        ((ushort4*)out)[i] = o;
    }
}

// ---------------------------------------------------------------------------
extern "C" void kernel_launch(void* const* d_in, const int* in_sizes, int n_in,
                              void* d_out, int out_size, void* d_ws, size_t ws_size,
                              hipStream_t stream)
{
    const float* in_hidden = (const float*)d_in[0];
    const float* enc_f     = (const float*)d_in[1];
    const int* attn_mask   = (const int*)d_in[2];
    const int* enc_attn_mask = (const int*)d_in[3];
    const float* sa_qkv_w  = (const float*)d_in[4];
    const float* sa_qkv_b  = (const float*)d_in[5];
    const float* sa_out_w  = (const float*)d_in[6];
    const float* sa_out_b  = (const float*)d_in[7];
    const float* sa_ln     = (const float*)d_in[8];
    const float* ca_qkv_w  = (const float*)d_in[9];
    const float* ca_qkv_b  = (const float*)d_in[10];
    const float* ca_out_w  = (const float*)d_in[11];
    const float* ca_out_b  = (const float*)d_in[12];
    const float* ca_ln     = (const float*)d_in[13];
    const float* o1_w      = (const float*)d_in[14];
    const float* o1_b      = (const float*)d_in[15];
    const float* o1_ln     = (const float*)d_in[16];
    const float* ffn_w     = (const float*)d_in[17];
    const float* ffn_b     = (const float*)d_in[18];
    const float* o2_w      = (const float*)d_in[19];
    const float* o2_b      = (const float*)d_in[20];
    const float* o2_ln     = (const float*)d_in[21];

    const size_t MH  = (size_t)MROWS * HDIM;   // 2,097,152
    const size_t Hsq = (size_t)HDIM * HDIM;    // 1,048,576
    const size_t HF  = (size_t)HDIM * FDIM;    // 4,194,304

    char* p = (char*)d_ws;
    unsigned short* wbf = (unsigned short*)p; p += (9 * Hsq + 2 * HF) * 2;  // ~34 MiB
    float* t2     = (float*)p; p += MH * 4;                                  // 8 MiB
    unsigned short* qb     = (unsigned short*)p; p += MH * 2;                // 4 MiB each
    unsigned short* kb     = (unsigned short*)p; p += MH * 2;
    unsigned short* vb     = (unsigned short*)p; p += MH * 2;
    unsigned short* ctx    = (unsigned short*)p; p += MH * 2;
    unsigned short* h      = (unsigned short*)p; p += MH * 2;
    unsigned short* enc_bf = (unsigned short*)p; p += MH * 2;
    unsigned short* attn1  = (unsigned short*)p; p += MH * 2;
    unsigned short* crossb = (unsigned short*)p; p += MH * 2;
    unsigned short* attn2  = (unsigned short*)p; p += MH * 2;
    unsigned short* tmp8b  = (unsigned short*)p; p += (size_t)MROWS * FDIM * 2; // 16 MiB

    unsigned short* w_saqkv = wbf;                 // [3072][1024]
    unsigned short* w_saout = wbf + 3 * Hsq;
    unsigned short* w_caqkv = wbf + 4 * Hsq;       // [3072][1024]
    unsigned short* w_caout = wbf + 7 * Hsq;
    unsigned short* w_o1    = wbf + 8 * Hsq;
    unsigned short* w_ffn   = wbf + 9 * Hsq;       // [4096][1024]
    unsigned short* w_o2    = wbf + 9 * Hsq + HF;  // [1024][4096]

    cvt_bf16_kernel<<<(MH / 4 + 255) / 256, 256, 0, stream>>>(in_hidden, h, MH / 4);
    cvt_bf16_kernel<<<(MH / 4 + 255) / 256, 256, 0, stream>>>(enc_f, enc_bf, MH / 4);

    for (int l = 0; l < LNUM; ++l) {
        // ---- weight convert+transpose for this layer ----
        convtrans_kernel<<<dim3(HDIM / 64, HDIM / 64, 3), 256, 0, stream>>>(
            sa_qkv_w + (size_t)l * 3 * Hsq, w_saqkv, HDIM, HDIM);
        convtrans_kernel<<<dim3(HDIM / 64, HDIM / 64, 1), 256, 0, stream>>>(
            sa_out_w + (size_t)l * Hsq, w_saout, HDIM, HDIM);
        convtrans_kernel<<<dim3(HDIM / 64, HDIM / 64, 3), 256, 0, stream>>>(
            ca_qkv_w + (size_t)l * 3 * Hsq, w_caqkv, HDIM, HDIM);
        convtrans_kernel<<<dim3(HDIM / 64, HDIM / 64, 1), 256, 0, stream>>>(
            ca_out_w + (size_t)l * Hsq, w_caout, HDIM, HDIM);
        convtrans_kernel<<<dim3(HDIM / 64, HDIM / 64, 1), 256, 0, stream>>>(
            o1_w + (size_t)l * Hsq, w_o1, HDIM, HDIM);
        convtrans_kernel<<<dim3(FDIM / 64, HDIM / 64, 1), 256, 0, stream>>>(
            ffn_w + (size_t)l * HF, w_ffn, HDIM, FDIM);
        convtrans_kernel<<<dim3(HDIM / 64, FDIM / 64, 1), 256, 0, stream>>>(
            o2_w + (size_t)l * HF, w_o2, FDIM, HDIM);

        // ---- self attention ----
        mfma_gemm_qkv<<<dim3(MROWS / 128, 3072 / 64), 256, 0, stream>>>(
            h, h, w_saqkv, sa_qkv_b + (size_t)l * 3 * HDIM, qb, kb, vb, MROWS, HDIM);
        flash_attn<<<dim3(SDIM / 64, NHEAD, BDIM), 256, 0, stream>>>(
            qb, kb, vb, attn_mask, ctx);
        mfma_gemm<64, false, false><<<dim3(MROWS / 128, HDIM / 64), 256, 0, stream>>>(
            ctx, w_saout, sa_out_b + (size_t)l * HDIM, t2, MROWS, HDIM, HDIM);
        ln_kernel<false><<<MROWS, 256, 0, stream>>>(t2, h, sa_ln + (size_t)l * 2 * HDIM, attn1);

        // ---- cross attention (residual = h; Q from h, KV from encoder) ----
        mfma_gemm_qkv<<<dim3(MROWS / 128, 3072 / 64), 256, 0, stream>>>(
            h, enc_bf, w_caqkv, ca_qkv_b + (size_t)l * 3 * HDIM, qb, kb, vb, MROWS, HDIM);
        flash_attn<<<dim3(SDIM / 64, NHEAD, BDIM), 256, 0, stream>>>(
            qb, kb, vb, enc_attn_mask, ctx);
        mfma_gemm<64, false, false><<<dim3(MROWS / 128, HDIM / 64), 256, 0, stream>>>(
            ctx, w_caout, ca_out_b + (size_t)l * HDIM, t2, MROWS, HDIM, HDIM);
        ln_kernel<false><<<MROWS, 256, 0, stream>>>(t2, h, ca_ln + (size_t)l * 2 * HDIM, crossb);

        // ---- output_1 ----
        mfma_gemm<64, false, false><<<dim3(MROWS / 128, HDIM / 64), 256, 0, stream>>>(
            attn1, w_o1, o1_b + (size_t)l * HDIM, t2, MROWS, HDIM, HDIM);
        ln_kernel<false><<<MROWS, 256, 0, stream>>>(t2, crossb, o1_ln + (size_t)l * 2 * HDIM, attn2);

        // ---- FFN ----
        mfma_gemm<128, true, true><<<dim3(MROWS / 128, FDIM / 128), 256, 0, stream>>>(
            attn2, w_ffn, ffn_b + (size_t)l * FDIM, tmp8b, MROWS, FDIM, HDIM);
        mfma_gemm<64, false, false><<<dim3(MROWS / 128, HDIM / 64), 256, 0, stream>>>(
            tmp8b, w_o2, o2_b + (size_t)l * HDIM, t2, MROWS, HDIM, FDIM);
        if (l == LNUM - 1)
            ln_kernel<true><<<MROWS, 256, 0, stream>>>(
                t2, attn2, o2_ln + (size_t)l * 2 * HDIM, (float*)d_out);
        else
            ln_kernel<false><<<MROWS, 256, 0, stream>>>(
                t2, attn2, o2_ln + (size_t)l * 2 * HDIM, h);
    }
}

// Round 2
// 2068.813 us; speedup vs baseline: 1.1750x; 1.0237x over previous
//
#include <hip/hip_runtime.h>

// ---------------------------------------------------------------------------
// T5 backbone forward, round 5:
//  - GEMM BM templatized; BM=64 for the grid-starved N=1024 GEMMs and QKV
//    (grid 256 -> 512/1536 blocks, 1 -> 2+ blocks/CU: cross-block overlap
//    hides the per-block barrier/vmcnt drain that 1 block/CU cannot)
//  - FFN1 stays 128x128 (already 2/CU, best MFMA:ds_read ratio)
//  - LN loads vectorized (float4 / ushort4)
//  - keeps round-4 double-buffered pipeline + XOR chunk-swizzle
// ---------------------------------------------------------------------------

#define LNUM 6
#define HDIM 1024
#define NHEAD 16
#define DHEAD 64
#define BDIM 4
#define SDIM 512
#define FDIM 4096
#define MROWS (BDIM * SDIM)   // 2048

typedef __bf16 bf16_t;
typedef bf16_t bf16x8 __attribute__((ext_vector_type(8)));
typedef float f32x4 __attribute__((ext_vector_type(4)));

__device__ __forceinline__ float bf2f(unsigned short u) {
    union { unsigned int i; float f; } x;
    x.i = ((unsigned int)u) << 16;
    return x.f;
}

__device__ __forceinline__ unsigned short f2bf(float f) {
    union { float f; unsigned int i; } u;
    u.f = f;
    unsigned int x = u.i;
    unsigned int lsb = (x >> 16) & 1u;
    x += 0x7fffu + lsb;           // round-to-nearest-even
    return (unsigned short)(x >> 16);
}

// async global->LDS, 16 bytes per lane; lds dest = wave-uniform base + lane*16
__device__ __forceinline__ void async16(const unsigned short* g, unsigned short* l) {
    __builtin_amdgcn_global_load_lds(
        (const __attribute__((address_space(1))) unsigned int*)g,
        (__attribute__((address_space(3))) unsigned int*)l, 16, 0, 0);
}

// ---------------------------------------------------------------------------
// MFMA GEMM: C[M,N] = A[M,K](bf16) @ BT[N,K](bf16)^T + bias(f32)
// BK=64, 256 threads (4 waves as 2x2), per-wave (BM/2) x (BN/2) output.
// Double-buffered LDS prefetch; XOR chunk-swizzled tiles.
// ---------------------------------------------------------------------------
template<int BM, int BN, bool GELU, bool OUTBF16>
__global__ __launch_bounds__(256) void mfma_gemm(
    const unsigned short* __restrict__ A,
    const unsigned short* __restrict__ BT,
    const float* __restrict__ bias,
    void* __restrict__ Cv,
    int M, int N, int K)
{
    constexpr int BK = 64;
    constexpr int MI = BM / 32;
    constexpr int NJ = BN / 32;

    __shared__ unsigned short As[2][BM][BK];
    __shared__ unsigned short Bs[2][BN][BK];

    const int t = threadIdx.x;
    const int w = t >> 6;
    const int lane = t & 63;
    const int quad = lane >> 4;
    const int cm = lane & 15;
    const int wrow = (w >> 1) * (BM / 2);
    const int wcol = (w & 1) * (BN / 2);
    const int row0 = blockIdx.x * BM;
    const int col0 = blockIdx.y * BN;

    f32x4 acc[MI][NJ] = {};

    const int lrow = lane >> 3;
    // pre-swizzled source chunk: physical LDS chunk (lane&7) of row lrow gets
    // logical chunk (lane&7)^lrow  =>  read side XORs by (row&7) to recover
    const int lcol = ((lane & 7) ^ lrow) * 8;
    const int sw = cm & 7;

    auto stage = [&](int buf, int k0) {
#pragma unroll
        for (int j = 0; j < BM / 32; ++j) {
            int mb = w * (BM / 4) + j * 8;
            async16(A + (size_t)(row0 + mb + lrow) * K + k0 + lcol, &As[buf][mb][0]);
        }
#pragma unroll
        for (int j = 0; j < BN / 32; ++j) {
            int nb = w * (BN / 4) + j * 8;
            async16(BT + (size_t)(col0 + nb + lrow) * K + k0 + lcol, &Bs[buf][nb][0]);
        }
    };

    stage(0, 0);
    __syncthreads();   // compiler emits vmcnt(0) drain before barrier

    int cur = 0;
    for (int k0 = 0; k0 < K; k0 += BK) {
        if (k0 + BK < K) stage(cur ^ 1, k0 + BK);   // prefetch next tile

#pragma unroll
        for (int kk = 0; kk < BK; kk += 32) {
            const int cc = kk >> 3;                  // logical chunk base (0 or 4)
            bf16x8 av[MI], bv[NJ];
#pragma unroll
            for (int i = 0; i < MI; ++i)
                av[i] = *(const bf16x8*)&As[cur][wrow + 16 * i + cm][((cc + quad) ^ sw) * 8];
#pragma unroll
            for (int j = 0; j < NJ; ++j)
                bv[j] = *(const bf16x8*)&Bs[cur][wcol + 16 * j + cm][((cc + quad) ^ sw) * 8];
#pragma unroll
            for (int i = 0; i < MI; ++i)
#pragma unroll
                for (int j = 0; j < NJ; ++j)
                    acc[i][j] = __builtin_amdgcn_mfma_f32_16x16x32_bf16(
                        av[i], bv[j], acc[i][j], 0, 0, 0);
        }
        __syncthreads();   // drains prefetch vmcnt + guards buffer reuse
        cur ^= 1;
    }

#pragma unroll
    for (int j = 0; j < NJ; ++j) {
        int col = col0 + wcol + 16 * j + cm;
        float bb = bias[col];
#pragma unroll
        for (int i = 0; i < MI; ++i) {
#pragma unroll
            for (int r = 0; r < 4; ++r) {
                int row = row0 + wrow + 16 * i + quad * 4 + r;
                float c = acc[i][j][r] + bb;
                if (GELU) {
                    float u = 0.7978845608028654f * (c + 0.044715f * c * c * c);
                    c = 0.5f * c * (1.0f + tanhf(u));
                }
                if (OUTBF16)
                    ((unsigned short*)Cv)[(size_t)row * N + col] = f2bf(c);
                else
                    ((float*)Cv)[(size_t)row * N + col] = c;
            }
        }
    }
}

// ---------------------------------------------------------------------------
// Fused QKV GEMM with dual A: col block 0 (Q) reads Aq, blocks 1/2 (K,V) read
// Akv. BT[3072,K]^T + bias[3072] -> q/k/v bf16 [M][1024].
// Same pipeline + swizzle; BM=64 for occupancy.
// ---------------------------------------------------------------------------
template<int BM>
__global__ __launch_bounds__(256) void mfma_gemm_qkv(
    const unsigned short* __restrict__ Aq,
    const unsigned short* __restrict__ Akv,
    const unsigned short* __restrict__ BT,
    const float* __restrict__ bias,
    unsigned short* __restrict__ qo,
    unsigned short* __restrict__ ko,
    unsigned short* __restrict__ vo,
    int M, int K)
{
    constexpr int BK = 64;
    constexpr int BN = 64;
    constexpr int MI = BM / 32;
    constexpr int NJ = 2;

    __shared__ unsigned short As[2][BM][BK];
    __shared__ unsigned short Bs[2][BN][BK];

    const int t = threadIdx.x;
    const int w = t >> 6;
    const int lane = t & 63;
    const int quad = lane >> 4;
    const int cm = lane & 15;
    const int wrow = (w >> 1) * (BM / 2);
    const int wcol = (w & 1) * 32;
    const int row0 = blockIdx.x * BM;
    const int col0 = blockIdx.y * BN;      // 0..3071

    const int which = col0 >> 10;
    const unsigned short* __restrict__ A = (which == 0) ? Aq : Akv;

    f32x4 acc[MI][NJ] = {};

    const int lrow = lane >> 3;
    const int lcol = ((lane & 7) ^ lrow) * 8;
    const int sw = cm & 7;

    auto stage = [&](int buf, int k0) {
#pragma unroll
        for (int j = 0; j < BM / 32; ++j) {
            int mb = w * (BM / 4) + j * 8;
            async16(A + (size_t)(row0 + mb + lrow) * K + k0 + lcol, &As[buf][mb][0]);
        }
#pragma unroll
        for (int j = 0; j < NJ; ++j) {
            int nb = w * 16 + j * 8;
            async16(BT + (size_t)(col0 + nb + lrow) * K + k0 + lcol, &Bs[buf][nb][0]);
        }
    };

    stage(0, 0);
    __syncthreads();

    int cur = 0;
    for (int k0 = 0; k0 < K; k0 += BK) {
        if (k0 + BK < K) stage(cur ^ 1, k0 + BK);

#pragma unroll
        for (int kk = 0; kk < BK; kk += 32) {
            const int cc = kk >> 3;
            bf16x8 av[MI], bv[NJ];
#pragma unroll
            for (int i = 0; i < MI; ++i)
                av[i] = *(const bf16x8*)&As[cur][wrow + 16 * i + cm][((cc + quad) ^ sw) * 8];
#pragma unroll
            for (int j = 0; j < NJ; ++j)
                bv[j] = *(const bf16x8*)&Bs[cur][wcol + 16 * j + cm][((cc + quad) ^ sw) * 8];
#pragma unroll
            for (int i = 0; i < MI; ++i)
#pragma unroll
                for (int j = 0; j < NJ; ++j)
                    acc[i][j] = __builtin_amdgcn_mfma_f32_16x16x32_bf16(
                        av[i], bv[j], acc[i][j], 0, 0, 0);
        }
        __syncthreads();
        cur ^= 1;
    }

    unsigned short* dst = (which == 0) ? qo : (which == 1) ? ko : vo;
    const int cbase = col0 & 1023;

#pragma unroll
    for (int j = 0; j < NJ; ++j) {
        int col = col0 + wcol + 16 * j + cm;
        float bb = bias[col];
        int coll = cbase + wcol + 16 * j + cm;
#pragma unroll
        for (int i = 0; i < MI; ++i) {
#pragma unroll
            for (int r = 0; r < 4; ++r) {
                int row = row0 + wrow + 16 * i + quad * 4 + r;
                dst[(size_t)row * HDIM + coll] = f2bf(acc[i][j][r] + bb);
            }
        }
    }
}

// ---------------------------------------------------------------------------
// Flash attention: grid (S/64, NH, B), 256 threads (4 waves).
// Each wave owns 16 q-rows; KV tiles of 64; online softmax; ctx bf16 out.
// Qs/Ks XOR chunk-swizzled (manual staging -> swizzle the store address).
// ---------------------------------------------------------------------------
__global__ __launch_bounds__(256) void flash_attn(
    const unsigned short* __restrict__ q,
    const unsigned short* __restrict__ k,
    const unsigned short* __restrict__ v,
    const int* __restrict__ mask,
    unsigned short* __restrict__ ctx)
{
    __shared__ unsigned short Qs[64][64];
    __shared__ unsigned short Ks[64][64];
    __shared__ unsigned short Vs[64][72];      // transposed: Vs[d][j] (padded)
    __shared__ unsigned short Ps[4][16][72];   // per-wave P tile [m][j] (padded)

    const int t = threadIdx.x;
    const int w = t >> 6;
    const int lane = t & 63;
    const int quad = lane >> 4;
    const int cm = lane & 15;
    const int sw = cm & 7;

    const int q0 = blockIdx.x * 64;
    const int h = blockIdx.y;
    const int b = blockIdx.z;
    const size_t rowbase = (size_t)b * SDIM;
    const int hoff = h * DHEAD;

    // stage Q tile (64x64), swizzled chunks
#pragma unroll
    for (int l = 0; l < 2; ++l) {
        int idx = t + l * 256;           // 0..511
        int r = idx >> 3;                // 0..63
        int c = idx & 7;                 // logical chunk
        *(uint4*)&Qs[r][((c ^ (r & 7)) * 8)] =
            *(const uint4*)(q + (rowbase + q0 + r) * HDIM + hoff + c * 8);
    }

    float m_prev[4] = {-1e30f, -1e30f, -1e30f, -1e30f};
    float l_sum[4] = {0.0f, 0.0f, 0.0f, 0.0f};
    f32x4 oacc[4] = {};

    for (int j0 = 0; j0 < SDIM; j0 += 64) {
        __syncthreads();   // previous iteration's compute done before restaging
        // stage K tile (64x64, swizzled) and V tile transposed
#pragma unroll
        for (int l = 0; l < 2; ++l) {
            int idx = t + l * 256;
            int r = idx >> 3;
            int c = idx & 7;
            *(uint4*)&Ks[r][((c ^ (r & 7)) * 8)] =
                *(const uint4*)(k + (rowbase + j0 + r) * HDIM + hoff + c * 8);
        }
#pragma unroll
        for (int l = 0; l < 4; ++l) {
            int idx = t + l * 256;       // 0..1023
            int jj = idx >> 4;           // 0..63
            int d0 = (idx & 15) * 4;
            ushort4 vv = *(const ushort4*)(v + (rowbase + j0 + jj) * HDIM + hoff + d0);
            Vs[d0 + 0][jj] = vv.x;
            Vs[d0 + 1][jj] = vv.y;
            Vs[d0 + 2][jj] = vv.z;
            Vs[d0 + 3][jj] = vv.w;
        }
        __syncthreads();

        // S = Q K^T for this wave's 16 rows x 64 kv cols
        f32x4 sacc[4] = {};
#pragma unroll
        for (int kk = 0; kk < 64; kk += 32) {
            const int cc = kk >> 3;
            bf16x8 av = *(const bf16x8*)&Qs[w * 16 + cm][((cc + quad) ^ sw) * 8];
#pragma unroll
            for (int j2 = 0; j2 < 4; ++j2) {
                bf16x8 bv = *(const bf16x8*)&Ks[j2 * 16 + cm][((cc + quad) ^ sw) * 8];
                sacc[j2] = __builtin_amdgcn_mfma_f32_16x16x32_bf16(av, bv, sacc[j2], 0, 0, 0);
            }
        }

        // mask adders for this lane's 4 columns
        float madd[4];
#pragma unroll
        for (int j2 = 0; j2 < 4; ++j2)
            madd[j2] = (1.0f - (float)mask[b * SDIM + j0 + j2 * 16 + cm]) * -10000.0f;

        // online softmax per row r (rows quad*4+r of the wave's 16)
#pragma unroll
        for (int r = 0; r < 4; ++r) {
            float s0 = sacc[0][r] * 0.125f + madd[0];
            float s1 = sacc[1][r] * 0.125f + madd[1];
            float s2 = sacc[2][r] * 0.125f + madd[2];
            float s3 = sacc[3][r] * 0.125f + madd[3];
            float rm = fmaxf(fmaxf(s0, s1), fmaxf(s2, s3));
#pragma unroll
            for (int mo = 1; mo < 16; mo <<= 1)
                rm = fmaxf(rm, __shfl_xor(rm, mo, 64));
            float new_m = fmaxf(m_prev[r], rm);
            float alpha = __expf(m_prev[r] - new_m);
            m_prev[r] = new_m;
            float p0 = __expf(s0 - new_m);
            float p1 = __expf(s1 - new_m);
            float p2 = __expf(s2 - new_m);
            float p3 = __expf(s3 - new_m);
            float rs = p0 + p1 + p2 + p3;
#pragma unroll
            for (int mo = 1; mo < 16; mo <<= 1)
                rs += __shfl_xor(rs, mo, 64);
            l_sum[r] = l_sum[r] * alpha + rs;
#pragma unroll
            for (int d2 = 0; d2 < 4; ++d2)
                oacc[d2][r] *= alpha;
            int prow = quad * 4 + r;
            Ps[w][prow][0 * 16 + cm] = f2bf(p0);
            Ps[w][prow][1 * 16 + cm] = f2bf(p1);
            Ps[w][prow][2 * 16 + cm] = f2bf(p2);
            Ps[w][prow][3 * 16 + cm] = f2bf(p3);
        }
        // wave-synchronous: own wave's Ps writes visible after lgkmcnt (compiler)

        // O += P V
#pragma unroll
        for (int kk = 0; kk < 64; kk += 32) {
            bf16x8 pa = *(const bf16x8*)&Ps[w][cm][kk + quad * 8];
#pragma unroll
            for (int d2 = 0; d2 < 4; ++d2) {
                bf16x8 bv = *(const bf16x8*)&Vs[d2 * 16 + cm][kk + quad * 8];
                oacc[d2] = __builtin_amdgcn_mfma_f32_16x16x32_bf16(pa, bv, oacc[d2], 0, 0, 0);
            }
        }
    }

    // epilogue: divide by l, write ctx
#pragma unroll
    for (int r = 0; r < 4; ++r) {
        float inv = 1.0f / l_sum[r];
        int row = q0 + w * 16 + quad * 4 + r;
#pragma unroll
        for (int d2 = 0; d2 < 4; ++d2) {
            ctx[(rowbase + row) * HDIM + hoff + d2 * 16 + cm] = f2bf(oacc[d2][r] * inv);
        }
    }
}

// ---------------------------------------------------------------------------
// Weight convert + transpose: fp32 [K][N] -> bf16 [N][K]. 64x64 tiles.
// ---------------------------------------------------------------------------
__global__ __launch_bounds__(256) void convtrans_kernel(
    const float* __restrict__ in, unsigned short* __restrict__ out, int K, int N)
{
    __shared__ unsigned short tile[64][72];
    const size_t moff = (size_t)blockIdx.z * K * N;
    const int n0 = blockIdx.x * 64, k0 = blockIdx.y * 64;
    const int t = threadIdx.x;
#pragma unroll
    for (int l = 0; l < 4; ++l) {
        int idx = t + l * 256;
        int kk = idx >> 4;
        int nn = (idx & 15) * 4;
        float4 v = *(const float4*)(in + moff + (size_t)(k0 + kk) * N + n0 + nn);
        tile[nn + 0][kk] = f2bf(v.x);
        tile[nn + 1][kk] = f2bf(v.y);
        tile[nn + 2][kk] = f2bf(v.z);
        tile[nn + 3][kk] = f2bf(v.w);
    }
    __syncthreads();
#pragma unroll
    for (int l = 0; l < 2; ++l) {
        int c = t + l * 256;
        int nn = c >> 3;
        int kk = (c & 7) * 8;
        *(uint4*)(out + moff + (size_t)(n0 + nn) * K + k0 + kk) =
            *(const uint4*)&tile[nn][kk];
    }
}

// ---------------------------------------------------------------------------
// Fused residual + LayerNorm: out = LN(x(f32) + resid(bf16)) * g + b
// Vectorized loads: one float4 + one ushort4 per thread.
// ---------------------------------------------------------------------------
template<bool OUTF32>
__global__ __launch_bounds__(256) void ln_kernel(
    const float* __restrict__ x, const unsigned short* __restrict__ resid,
    const float* __restrict__ ln, void* __restrict__ out)
{
    const int row = blockIdx.x;
    const float* xr = x + (size_t)row * HDIM;
    const unsigned short* rr = resid + (size_t)row * HDIM;
    const int t = threadIdx.x;
    __shared__ float red[4];

    float4 xv = ((const float4*)xr)[t];
    ushort4 rv = ((const ushort4*)rr)[t];
    float z[4];
    z[0] = xv.x + bf2f(rv.x);
    z[1] = xv.y + bf2f(rv.y);
    z[2] = xv.z + bf2f(rv.z);
    z[3] = xv.w + bf2f(rv.w);
    float s = z[0] + z[1] + z[2] + z[3];
#pragma unroll
    for (int off = 32; off > 0; off >>= 1) s += __shfl_down(s, off, 64);
    if ((t & 63) == 0) red[t >> 6] = s;
    __syncthreads();
    s = red[0] + red[1] + red[2] + red[3];
    float mean = s * (1.0f / (float)HDIM);

    float vs = 0.0f;
#pragma unroll
    for (int i = 0; i < 4; ++i) {
        float d = z[i] - mean;
        vs += d * d;
    }
#pragma unroll
    for (int off = 32; off > 0; off >>= 1) vs += __shfl_down(vs, off, 64);
    __syncthreads();
    if ((t & 63) == 0) red[t >> 6] = vs;
    __syncthreads();
    vs = red[0] + red[1] + red[2] + red[3];
    float inv = rsqrtf(vs * (1.0f / (float)HDIM) + 1e-12f);

    const float* g = ln + 4 * t;
    const float* bb = ln + HDIM + 4 * t;
    if (OUTF32) {
        float4 o;
        o.x = (z[0] - mean) * inv * g[0] + bb[0];
        o.y = (z[1] - mean) * inv * g[1] + bb[1];
        o.z = (z[2] - mean) * inv * g[2] + bb[2];
        o.w = (z[3] - mean) * inv * g[3] + bb[3];
        ((float4*)((float*)out + (size_t)row * HDIM))[t] = o;
    } else {
        ushort4 o;
        o.x = f2bf((z[0] - mean) * inv * g[0] + bb[0]);
        o.y = f2bf((z[1] - mean) * inv * g[1] + bb[1]);
        o.z = f2bf((z[2] - mean) * inv * g[2] + bb[2]);
        o.w = f2bf((z[3] - mean) * inv * g[3] + bb[3]);
        ((ushort4*)((unsigned short*)out + (size_t)row * HDIM))[t] = o;
    }
}

__global__ __launch_bounds__(256) void cvt_bf16_kernel(
    const float* __restrict__ in, unsigned short* __restrict__ out, int n4)
{
    int i = blockIdx.x * 256 + threadIdx.x;
    if (i < n4) {
        float4 v = ((const float4*)in)[i];
        ushort4 o;
        o.x = f2bf(v.x); o.y = f2bf(v.y); o.z = f2bf(v.z); o.w = f2bf(v.w);
        ((ushort4*)out)[i] = o;
    }
}

// ---------------------------------------------------------------------------
extern "C" void kernel_launch(void* const* d_in, const int* in_sizes, int n_in,
                              void* d_out, int out_size, void* d_ws, size_t ws_size,
                              hipStream_t stream)
{
    const float* in_hidden = (const float*)d_in[0];
    const float* enc_f     = (const float*)d_in[1];
    const int* attn_mask   = (const int*)d_in[2];
    const int* enc_attn_mask = (const int*)d_in[3];
    const float* sa_qkv_w  = (const float*)d_in[4];
    const float* sa_qkv_b  = (const float*)d_in[5];
    const float* sa_out_w  = (const float*)d_in[6];
    const float* sa_out_b  = (const float*)d_in[7];
    const float* sa_ln     = (const float*)d_in[8];
    const float* ca_qkv_w  = (const float*)d_in[9];
    const float* ca_qkv_b  = (const float*)d_in[10];
    const float* ca_out_w  = (const float*)d_in[11];
    const float* ca_out_b  = (const float*)d_in[12];
    const float* ca_ln     = (const float*)d_in[13];
    const float* o1_w      = (const float*)d_in[14];
    const float* o1_b      = (const float*)d_in[15];
    const float* o1_ln     = (const float*)d_in[16];
    const float* ffn_w     = (const float*)d_in[17];
    const float* ffn_b     = (const float*)d_in[18];
    const float* o2_w      = (const float*)d_in[19];
    const float* o2_b      = (const float*)d_in[20];
    const float* o2_ln     = (const float*)d_in[21];

    const size_t MH  = (size_t)MROWS * HDIM;   // 2,097,152
    const size_t Hsq = (size_t)HDIM * HDIM;    // 1,048,576
    const size_t HF  = (size_t)HDIM * FDIM;    // 4,194,304

    char* p = (char*)d_ws;
    unsigned short* wbf = (unsigned short*)p; p += (9 * Hsq + 2 * HF) * 2;  // ~34 MiB
    float* t2     = (float*)p; p += MH * 4;                                  // 8 MiB
    unsigned short* qb     = (unsigned short*)p; p += MH * 2;                // 4 MiB each
    unsigned short* kb     = (unsigned short*)p; p += MH * 2;
    unsigned short* vb     = (unsigned short*)p; p += MH * 2;
    unsigned short* ctx    = (unsigned short*)p; p += MH * 2;
    unsigned short* h      = (unsigned short*)p; p += MH * 2;
    unsigned short* enc_bf = (unsigned short*)p; p += MH * 2;
    unsigned short* attn1  = (unsigned short*)p; p += MH * 2;
    unsigned short* crossb = (unsigned short*)p; p += MH * 2;
    unsigned short* attn2  = (unsigned short*)p; p += MH * 2;
    unsigned short* tmp8b  = (unsigned short*)p; p += (size_t)MROWS * FDIM * 2; // 16 MiB

    unsigned short* w_saqkv = wbf;                 // [3072][1024]
    unsigned short* w_saout = wbf + 3 * Hsq;
    unsigned short* w_caqkv = wbf + 4 * Hsq;       // [3072][1024]
    unsigned short* w_caout = wbf + 7 * Hsq;
    unsigned short* w_o1    = wbf + 8 * Hsq;
    unsigned short* w_ffn   = wbf + 9 * Hsq;       // [4096][1024]
    unsigned short* w_o2    = wbf + 9 * Hsq + HF;  // [1024][4096]

    cvt_bf16_kernel<<<(MH / 4 + 255) / 256, 256, 0, stream>>>(in_hidden, h, MH / 4);
    cvt_bf16_kernel<<<(MH / 4 + 255) / 256, 256, 0, stream>>>(enc_f, enc_bf, MH / 4);

    for (int l = 0; l < LNUM; ++l) {
        // ---- weight convert+transpose for this layer ----
        convtrans_kernel<<<dim3(HDIM / 64, HDIM / 64, 3), 256, 0, stream>>>(
            sa_qkv_w + (size_t)l * 3 * Hsq, w_saqkv, HDIM, HDIM);
        convtrans_kernel<<<dim3(HDIM / 64, HDIM / 64, 1), 256, 0, stream>>>(
            sa_out_w + (size_t)l * Hsq, w_saout, HDIM, HDIM);
        convtrans_kernel<<<dim3(HDIM / 64, HDIM / 64, 3), 256, 0, stream>>>(
            ca_qkv_w + (size_t)l * 3 * Hsq, w_caqkv, HDIM, HDIM);
        convtrans_kernel<<<dim3(HDIM / 64, HDIM / 64, 1), 256, 0, stream>>>(
            ca_out_w + (size_t)l * Hsq, w_caout, HDIM, HDIM);
        convtrans_kernel<<<dim3(HDIM / 64, HDIM / 64, 1), 256, 0, stream>>>(
            o1_w + (size_t)l * Hsq, w_o1, HDIM, HDIM);
        convtrans_kernel<<<dim3(FDIM / 64, HDIM / 64, 1), 256, 0, stream>>>(
            ffn_w + (size_t)l * HF, w_ffn, HDIM, FDIM);
        convtrans_kernel<<<dim3(HDIM / 64, FDIM / 64, 1), 256, 0, stream>>>(
            o2_w + (size_t)l * HF, w_o2, FDIM, HDIM);

        // ---- self attention ----
        mfma_gemm_qkv<64><<<dim3(MROWS / 64, 3072 / 64), 256, 0, stream>>>(
            h, h, w_saqkv, sa_qkv_b + (size_t)l * 3 * HDIM, qb, kb, vb, MROWS, HDIM);
        flash_attn<<<dim3(SDIM / 64, NHEAD, BDIM), 256, 0, stream>>>(
            qb, kb, vb, attn_mask, ctx);
        mfma_gemm<64, 64, false, false><<<dim3(MROWS / 64, HDIM / 64), 256, 0, stream>>>(
            ctx, w_saout, sa_out_b + (size_t)l * HDIM, t2, MROWS, HDIM, HDIM);
        ln_kernel<false><<<MROWS, 256, 0, stream>>>(t2, h, sa_ln + (size_t)l * 2 * HDIM, attn1);

        // ---- cross attention (residual = h; Q from h, KV from encoder) ----
        mfma_gemm_qkv<64><<<dim3(MROWS / 64, 3072 / 64), 256, 0, stream>>>(
            h, enc_bf, w_caqkv, ca_qkv_b + (size_t)l * 3 * HDIM, qb, kb, vb, MROWS, HDIM);
        flash_attn<<<dim3(SDIM / 64, NHEAD, BDIM), 256, 0, stream>>>(
            qb, kb, vb, enc_attn_mask, ctx);
        mfma_gemm<64, 64, false, false><<<dim3(MROWS / 64, HDIM / 64), 256, 0, stream>>>(
            ctx, w_caout, ca_out_b + (size_t)l * HDIM, t2, MROWS, HDIM, HDIM);
        ln_kernel<false><<<MROWS, 256, 0, stream>>>(t2, h, ca_ln + (size_t)l * 2 * HDIM, crossb);

        // ---- output_1 ----
        mfma_gemm<64, 64, false, false><<<dim3(MROWS / 64, HDIM / 64), 256, 0, stream>>>(
            attn1, w_o1, o1_b + (size_t)l * HDIM, t2, MROWS, HDIM, HDIM);
        ln_kernel<false><<<MROWS, 256, 0, stream>>>(t2, crossb, o1_ln + (size_t)l * 2 * HDIM, attn2);

        // ---- FFN ----
        mfma_gemm<128, 128, true, true><<<dim3(MROWS / 128, FDIM / 128), 256, 0, stream>>>(
            attn2, w_ffn, ffn_b + (size_t)l * FDIM, tmp8b, MROWS, FDIM, HDIM);
        mfma_gemm<64, 64, false, false><<<dim3(MROWS / 64, HDIM / 64), 256, 0, stream>>>(
            tmp8b, w_o2, o2_b + (size_t)l * HDIM, t2, MROWS, HDIM, FDIM);
        if (l == LNUM - 1)
            ln_kernel<true><<<MROWS, 256, 0, stream>>>(
                t2, attn2, o2_ln + (size_t)l * 2 * HDIM, (float*)d_out);
        else
            ln_kernel<false><<<MROWS, 256, 0, stream>>>(
                t2, attn2, o2_ln + (size_t)l * 2 * HDIM, h);
    }
}

// Round 3
// 2012.261 us; speedup vs baseline: 1.2080x; 1.0281x over previous
//
#include <hip/hip_runtime.h>

// ---------------------------------------------------------------------------
// T5 backbone forward, round 6:
//  - counted-vmcnt depth-2 pipeline (T4): raw s_barrier + s_waitcnt vmcnt(LPT),
//    never draining to 0 in the K-loop -> prefetch stays in flight across
//    barriers (kills the __syncthreads vmcnt(0) drain = ~70% of GEMM time)
//  - FFN1 retiled to 64x128 (grid 1024, 48KB LDS, 3 blocks/CU)
//  - all 7 weight convert/transpose launches fused into ONE kernel per layer
//  - keeps XOR chunk-swizzle (bank conflicts = 0 confirmed by rocprof)
// ---------------------------------------------------------------------------

#define LNUM 6
#define HDIM 1024
#define NHEAD 16
#define DHEAD 64
#define BDIM 4
#define SDIM 512
#define FDIM 4096
#define MROWS (BDIM * SDIM)   // 2048
#define HSQ (HDIM * HDIM)

typedef __bf16 bf16_t;
typedef bf16_t bf16x8 __attribute__((ext_vector_type(8)));
typedef float f32x4 __attribute__((ext_vector_type(4)));

__device__ __forceinline__ float bf2f(unsigned short u) {
    union { unsigned int i; float f; } x;
    x.i = ((unsigned int)u) << 16;
    return x.f;
}

__device__ __forceinline__ unsigned short f2bf(float f) {
    union { float f; unsigned int i; } u;
    u.f = f;
    unsigned int x = u.i;
    unsigned int lsb = (x >> 16) & 1u;
    x += 0x7fffu + lsb;           // round-to-nearest-even
    return (unsigned short)(x >> 16);
}

// async global->LDS, 16 bytes per lane; lds dest = wave-uniform base + lane*16
__device__ __forceinline__ void async16(const unsigned short* g, unsigned short* l) {
    __builtin_amdgcn_global_load_lds(
        (const __attribute__((address_space(1))) unsigned int*)g,
        (__attribute__((address_space(3))) unsigned int*)l, 16, 0, 0);
}

template<int N>
__device__ __forceinline__ void s_wait_vmcnt() {
    asm volatile("s_waitcnt vmcnt(%0)" :: "n"(N) : "memory");
}

// ---------------------------------------------------------------------------
// MFMA GEMM: C[M,N] = A[M,K](bf16) @ BT[N,K](bf16)^T + bias(f32)
// BK=64, 256 threads (4 waves as 2x2), per-wave (BM/2) x (BN/2) output.
// Counted-vmcnt depth-2 pipeline; XOR chunk-swizzled tiles.
// ---------------------------------------------------------------------------
template<int BM, int BN, bool GELU, bool OUTBF16>
__global__ __launch_bounds__(256) void mfma_gemm(
    const unsigned short* __restrict__ A,
    const unsigned short* __restrict__ BT,
    const float* __restrict__ bias,
    void* __restrict__ Cv,
    int M, int N, int K)
{
    constexpr int BK = 64;
    constexpr int MI = BM / 32;
    constexpr int NJ = BN / 32;
    constexpr int LPT = BM / 32 + BN / 32;   // global_load_lds per wave per tile

    __shared__ unsigned short As[2][BM][BK];
    __shared__ unsigned short Bs[2][BN][BK];

    const int t = threadIdx.x;
    const int w = t >> 6;
    const int lane = t & 63;
    const int quad = lane >> 4;
    const int cm = lane & 15;
    const int wrow = (w >> 1) * (BM / 2);
    const int wcol = (w & 1) * (BN / 2);
    const int row0 = blockIdx.x * BM;
    const int col0 = blockIdx.y * BN;

    f32x4 acc[MI][NJ] = {};

    const int lrow = lane >> 3;
    // pre-swizzled source chunk: physical LDS chunk (lane&7) of row lrow gets
    // logical chunk (lane&7)^lrow  =>  read side XORs by (row&7) to recover
    const int lcol = ((lane & 7) ^ lrow) * 8;
    const int sw = cm & 7;

    auto stage = [&](int buf, int k0) {
#pragma unroll
        for (int j = 0; j < BM / 32; ++j) {
            int mb = w * (BM / 4) + j * 8;
            async16(A + (size_t)(row0 + mb + lrow) * K + k0 + lcol, &As[buf][mb][0]);
        }
#pragma unroll
        for (int j = 0; j < BN / 32; ++j) {
            int nb = w * (BN / 4) + j * 8;
            async16(BT + (size_t)(col0 + nb + lrow) * K + k0 + lcol, &Bs[buf][nb][0]);
        }
    };

    const int NT = K / BK;
    stage(0, 0);
    int cur = 0;
    for (int ti = 0; ti < NT; ++ti) {
        if (ti + 1 < NT) {
            stage(cur ^ 1, (ti + 1) * BK);   // issue next tile (other buffer)
            s_wait_vmcnt<LPT>();             // wait ONLY for tile ti's loads
        } else {
            s_wait_vmcnt<0>();               // final tile: full drain once
        }
        __builtin_amdgcn_s_barrier();        // all waves' tile-ti loads landed
        __builtin_amdgcn_sched_barrier(0);   // no ds_read hoists above this

#pragma unroll
        for (int kk = 0; kk < BK; kk += 32) {
            const int cc = kk >> 3;                  // logical chunk base (0 or 4)
            bf16x8 av[MI], bv[NJ];
#pragma unroll
            for (int i = 0; i < MI; ++i)
                av[i] = *(const bf16x8*)&As[cur][wrow + 16 * i + cm][((cc + quad) ^ sw) * 8];
#pragma unroll
            for (int j = 0; j < NJ; ++j)
                bv[j] = *(const bf16x8*)&Bs[cur][wcol + 16 * j + cm][((cc + quad) ^ sw) * 8];
#pragma unroll
            for (int i = 0; i < MI; ++i)
#pragma unroll
                for (int j = 0; j < NJ; ++j)
                    acc[i][j] = __builtin_amdgcn_mfma_f32_16x16x32_bf16(
                        av[i], bv[j], acc[i][j], 0, 0, 0);
        }

        __builtin_amdgcn_sched_barrier(0);   // no ds_read sinks below this
        __builtin_amdgcn_s_barrier();        // buf[cur] free for reuse
        cur ^= 1;
    }

#pragma unroll
    for (int j = 0; j < NJ; ++j) {
        int col = col0 + wcol + 16 * j + cm;
        float bb = bias[col];
#pragma unroll
        for (int i = 0; i < MI; ++i) {
#pragma unroll
            for (int r = 0; r < 4; ++r) {
                int row = row0 + wrow + 16 * i + quad * 4 + r;
                float c = acc[i][j][r] + bb;
                if (GELU) {
                    float u = 0.7978845608028654f * (c + 0.044715f * c * c * c);
                    c = 0.5f * c * (1.0f + tanhf(u));
                }
                if (OUTBF16)
                    ((unsigned short*)Cv)[(size_t)row * N + col] = f2bf(c);
                else
                    ((float*)Cv)[(size_t)row * N + col] = c;
            }
        }
    }
}

// ---------------------------------------------------------------------------
// Fused QKV GEMM with dual A: col block 0 (Q) reads Aq, blocks 1/2 (K,V) read
// Akv. BT[3072,K]^T + bias[3072] -> q/k/v bf16 [M][1024].
// Same counted-vmcnt pipeline + swizzle; BM=64 for occupancy.
// ---------------------------------------------------------------------------
template<int BM>
__global__ __launch_bounds__(256) void mfma_gemm_qkv(
    const unsigned short* __restrict__ Aq,
    const unsigned short* __restrict__ Akv,
    const unsigned short* __restrict__ BT,
    const float* __restrict__ bias,
    unsigned short* __restrict__ qo,
    unsigned short* __restrict__ ko,
    unsigned short* __restrict__ vo,
    int M, int K)
{
    constexpr int BK = 64;
    constexpr int BN = 64;
    constexpr int MI = BM / 32;
    constexpr int NJ = 2;
    constexpr int LPT = BM / 32 + BN / 32;

    __shared__ unsigned short As[2][BM][BK];
    __shared__ unsigned short Bs[2][BN][BK];

    const int t = threadIdx.x;
    const int w = t >> 6;
    const int lane = t & 63;
    const int quad = lane >> 4;
    const int cm = lane & 15;
    const int wrow = (w >> 1) * (BM / 2);
    const int wcol = (w & 1) * 32;
    const int row0 = blockIdx.x * BM;
    const int col0 = blockIdx.y * BN;      // 0..3071

    const int which = col0 >> 10;
    const unsigned short* __restrict__ A = (which == 0) ? Aq : Akv;

    f32x4 acc[MI][NJ] = {};

    const int lrow = lane >> 3;
    const int lcol = ((lane & 7) ^ lrow) * 8;
    const int sw = cm & 7;

    auto stage = [&](int buf, int k0) {
#pragma unroll
        for (int j = 0; j < BM / 32; ++j) {
            int mb = w * (BM / 4) + j * 8;
            async16(A + (size_t)(row0 + mb + lrow) * K + k0 + lcol, &As[buf][mb][0]);
        }
#pragma unroll
        for (int j = 0; j < NJ; ++j) {
            int nb = w * 16 + j * 8;
            async16(BT + (size_t)(col0 + nb + lrow) * K + k0 + lcol, &Bs[buf][nb][0]);
        }
    };

    const int NT = K / BK;
    stage(0, 0);
    int cur = 0;
    for (int ti = 0; ti < NT; ++ti) {
        if (ti + 1 < NT) {
            stage(cur ^ 1, (ti + 1) * BK);
            s_wait_vmcnt<LPT>();
        } else {
            s_wait_vmcnt<0>();
        }
        __builtin_amdgcn_s_barrier();
        __builtin_amdgcn_sched_barrier(0);

#pragma unroll
        for (int kk = 0; kk < BK; kk += 32) {
            const int cc = kk >> 3;
            bf16x8 av[MI], bv[NJ];
#pragma unroll
            for (int i = 0; i < MI; ++i)
                av[i] = *(const bf16x8*)&As[cur][wrow + 16 * i + cm][((cc + quad) ^ sw) * 8];
#pragma unroll
            for (int j = 0; j < NJ; ++j)
                bv[j] = *(const bf16x8*)&Bs[cur][wcol + 16 * j + cm][((cc + quad) ^ sw) * 8];
#pragma unroll
            for (int i = 0; i < MI; ++i)
#pragma unroll
                for (int j = 0; j < NJ; ++j)
                    acc[i][j] = __builtin_amdgcn_mfma_f32_16x16x32_bf16(
                        av[i], bv[j], acc[i][j], 0, 0, 0);
        }

        __builtin_amdgcn_sched_barrier(0);
        __builtin_amdgcn_s_barrier();
        cur ^= 1;
    }

    unsigned short* dst = (which == 0) ? qo : (which == 1) ? ko : vo;
    const int cbase = col0 & 1023;

#pragma unroll
    for (int j = 0; j < NJ; ++j) {
        int col = col0 + wcol + 16 * j + cm;
        float bb = bias[col];
        int coll = cbase + wcol + 16 * j + cm;
#pragma unroll
        for (int i = 0; i < MI; ++i) {
#pragma unroll
            for (int r = 0; r < 4; ++r) {
                int row = row0 + wrow + 16 * i + quad * 4 + r;
                dst[(size_t)row * HDIM + coll] = f2bf(acc[i][j][r] + bb);
            }
        }
    }
}

// ---------------------------------------------------------------------------
// Flash attention: grid (S/64, NH, B), 256 threads (4 waves).
// Each wave owns 16 q-rows; KV tiles of 64; online softmax; ctx bf16 out.
// Qs/Ks XOR chunk-swizzled (manual staging -> swizzle the store address).
// ---------------------------------------------------------------------------
__global__ __launch_bounds__(256) void flash_attn(
    const unsigned short* __restrict__ q,
    const unsigned short* __restrict__ k,
    const unsigned short* __restrict__ v,
    const int* __restrict__ mask,
    unsigned short* __restrict__ ctx)
{
    __shared__ unsigned short Qs[64][64];
    __shared__ unsigned short Ks[64][64];
    __shared__ unsigned short Vs[64][72];      // transposed: Vs[d][j] (padded)
    __shared__ unsigned short Ps[4][16][72];   // per-wave P tile [m][j] (padded)

    const int t = threadIdx.x;
    const int w = t >> 6;
    const int lane = t & 63;
    const int quad = lane >> 4;
    const int cm = lane & 15;
    const int sw = cm & 7;

    const int q0 = blockIdx.x * 64;
    const int h = blockIdx.y;
    const int b = blockIdx.z;
    const size_t rowbase = (size_t)b * SDIM;
    const int hoff = h * DHEAD;

    // stage Q tile (64x64), swizzled chunks
#pragma unroll
    for (int l = 0; l < 2; ++l) {
        int idx = t + l * 256;           // 0..511
        int r = idx >> 3;                // 0..63
        int c = idx & 7;                 // logical chunk
        *(uint4*)&Qs[r][((c ^ (r & 7)) * 8)] =
            *(const uint4*)(q + (rowbase + q0 + r) * HDIM + hoff + c * 8);
    }

    float m_prev[4] = {-1e30f, -1e30f, -1e30f, -1e30f};
    float l_sum[4] = {0.0f, 0.0f, 0.0f, 0.0f};
    f32x4 oacc[4] = {};

    for (int j0 = 0; j0 < SDIM; j0 += 64) {
        __syncthreads();   // previous iteration's compute done before restaging
        // stage K tile (64x64, swizzled) and V tile transposed
#pragma unroll
        for (int l = 0; l < 2; ++l) {
            int idx = t + l * 256;
            int r = idx >> 3;
            int c = idx & 7;
            *(uint4*)&Ks[r][((c ^ (r & 7)) * 8)] =
                *(const uint4*)(k + (rowbase + j0 + r) * HDIM + hoff + c * 8);
        }
#pragma unroll
        for (int l = 0; l < 4; ++l) {
            int idx = t + l * 256;       // 0..1023
            int jj = idx >> 4;           // 0..63
            int d0 = (idx & 15) * 4;
            ushort4 vv = *(const ushort4*)(v + (rowbase + j0 + jj) * HDIM + hoff + d0);
            Vs[d0 + 0][jj] = vv.x;
            Vs[d0 + 1][jj] = vv.y;
            Vs[d0 + 2][jj] = vv.z;
            Vs[d0 + 3][jj] = vv.w;
        }
        __syncthreads();

        // S = Q K^T for this wave's 16 rows x 64 kv cols
        f32x4 sacc[4] = {};
#pragma unroll
        for (int kk = 0; kk < 64; kk += 32) {
            const int cc = kk >> 3;
            bf16x8 av = *(const bf16x8*)&Qs[w * 16 + cm][((cc + quad) ^ sw) * 8];
#pragma unroll
            for (int j2 = 0; j2 < 4; ++j2) {
                bf16x8 bv = *(const bf16x8*)&Ks[j2 * 16 + cm][((cc + quad) ^ sw) * 8];
                sacc[j2] = __builtin_amdgcn_mfma_f32_16x16x32_bf16(av, bv, sacc[j2], 0, 0, 0);
            }
        }

        // mask adders for this lane's 4 columns
        float madd[4];
#pragma unroll
        for (int j2 = 0; j2 < 4; ++j2)
            madd[j2] = (1.0f - (float)mask[b * SDIM + j0 + j2 * 16 + cm]) * -10000.0f;

        // online softmax per row r (rows quad*4+r of the wave's 16)
#pragma unroll
        for (int r = 0; r < 4; ++r) {
            float s0 = sacc[0][r] * 0.125f + madd[0];
            float s1 = sacc[1][r] * 0.125f + madd[1];
            float s2 = sacc[2][r] * 0.125f + madd[2];
            float s3 = sacc[3][r] * 0.125f + madd[3];
            float rm = fmaxf(fmaxf(s0, s1), fmaxf(s2, s3));
#pragma unroll
            for (int mo = 1; mo < 16; mo <<= 1)
                rm = fmaxf(rm, __shfl_xor(rm, mo, 64));
            float new_m = fmaxf(m_prev[r], rm);
            float alpha = __expf(m_prev[r] - new_m);
            m_prev[r] = new_m;
            float p0 = __expf(s0 - new_m);
            float p1 = __expf(s1 - new_m);
            float p2 = __expf(s2 - new_m);
            float p3 = __expf(s3 - new_m);
            float rs = p0 + p1 + p2 + p3;
#pragma unroll
            for (int mo = 1; mo < 16; mo <<= 1)
                rs += __shfl_xor(rs, mo, 64);
            l_sum[r] = l_sum[r] * alpha + rs;
#pragma unroll
            for (int d2 = 0; d2 < 4; ++d2)
                oacc[d2][r] *= alpha;
            int prow = quad * 4 + r;
            Ps[w][prow][0 * 16 + cm] = f2bf(p0);
            Ps[w][prow][1 * 16 + cm] = f2bf(p1);
            Ps[w][prow][2 * 16 + cm] = f2bf(p2);
            Ps[w][prow][3 * 16 + cm] = f2bf(p3);
        }
        // wave-synchronous: own wave's Ps writes visible after lgkmcnt (compiler)

        // O += P V
#pragma unroll
        for (int kk = 0; kk < 64; kk += 32) {
            bf16x8 pa = *(const bf16x8*)&Ps[w][cm][kk + quad * 8];
#pragma unroll
            for (int d2 = 0; d2 < 4; ++d2) {
                bf16x8 bv = *(const bf16x8*)&Vs[d2 * 16 + cm][kk + quad * 8];
                oacc[d2] = __builtin_amdgcn_mfma_f32_16x16x32_bf16(pa, bv, oacc[d2], 0, 0, 0);
            }
        }
    }

    // epilogue: divide by l, write ctx
#pragma unroll
    for (int r = 0; r < 4; ++r) {
        float inv = 1.0f / l_sum[r];
        int row = q0 + w * 16 + quad * 4 + r;
#pragma unroll
        for (int d2 = 0; d2 < 4; ++d2) {
            ctx[(rowbase + row) * HDIM + hoff + d2 * 16 + cm] = f2bf(oacc[d2][r] * inv);
        }
    }
}

// ---------------------------------------------------------------------------
// Fused weight convert + transpose for ONE layer: all 7 matrices in one
// launch. fp32 [K][N] -> bf16 [N][K], 64x64 tiles, block-uniform decode.
// Tile layout: [0,2304) 9x HxH squares; [2304,3328) ffn 1024x4096;
// [3328,4352) o2 4096x1024.
// ---------------------------------------------------------------------------
__global__ __launch_bounds__(256) void convtrans_all(
    const float* __restrict__ sqkv, const float* __restrict__ sout,
    const float* __restrict__ cqkv, const float* __restrict__ cout,
    const float* __restrict__ o1w,  const float* __restrict__ ffnw,
    const float* __restrict__ o2w,
    unsigned short* __restrict__ dq,  unsigned short* __restrict__ dso,
    unsigned short* __restrict__ dcq, unsigned short* __restrict__ dco,
    unsigned short* __restrict__ do1, unsigned short* __restrict__ dffn,
    unsigned short* __restrict__ do2)
{
    __shared__ unsigned short tile[64][72];
    const int bid = blockIdx.x;
    const float* src;
    unsigned short* dst;
    int K, N, tt;
    if (bid < 2304) {
        int m = bid >> 8;        // 0..8
        tt = bid & 255;
        K = HDIM; N = HDIM;
        if (m < 3)      { src = sqkv + (size_t)m * HSQ;       dst = dq  + (size_t)m * HSQ; }
        else if (m < 6) { src = cqkv + (size_t)(m - 3) * HSQ; dst = dcq + (size_t)(m - 3) * HSQ; }
        else if (m == 6){ src = sout; dst = dso; }
        else if (m == 7){ src = cout; dst = dco; }
        else            { src = o1w;  dst = do1; }
    } else if (bid < 3328) {
        tt = bid - 2304; K = HDIM; N = FDIM; src = ffnw; dst = dffn;
    } else {
        tt = bid - 3328; K = FDIM; N = HDIM; src = o2w; dst = do2;
    }
    const int tn = N >> 6;
    const int n0 = (tt % tn) * 64;
    const int k0 = (tt / tn) * 64;
    const int t = threadIdx.x;
#pragma unroll
    for (int l = 0; l < 4; ++l) {
        int idx = t + l * 256;
        int kk = idx >> 4;
        int nn = (idx & 15) * 4;
        float4 v = *(const float4*)(src + (size_t)(k0 + kk) * N + n0 + nn);
        tile[nn + 0][kk] = f2bf(v.x);
        tile[nn + 1][kk] = f2bf(v.y);
        tile[nn + 2][kk] = f2bf(v.z);
        tile[nn + 3][kk] = f2bf(v.w);
    }
    __syncthreads();
#pragma unroll
    for (int l = 0; l < 2; ++l) {
        int c = t + l * 256;
        int nn = c >> 3;
        int kk = (c & 7) * 8;
        *(uint4*)(dst + (size_t)(n0 + nn) * K + k0 + kk) = *(const uint4*)&tile[nn][kk];
    }
}

// ---------------------------------------------------------------------------
// Fused residual + LayerNorm: out = LN(x(f32) + resid(bf16)) * g + b
// Vectorized loads: one float4 + one ushort4 per thread.
// ---------------------------------------------------------------------------
template<bool OUTF32>
__global__ __launch_bounds__(256) void ln_kernel(
    const float* __restrict__ x, const unsigned short* __restrict__ resid,
    const float* __restrict__ ln, void* __restrict__ out)
{
    const int row = blockIdx.x;
    const float* xr = x + (size_t)row * HDIM;
    const unsigned short* rr = resid + (size_t)row * HDIM;
    const int t = threadIdx.x;
    __shared__ float red[4];

    float4 xv = ((const float4*)xr)[t];
    ushort4 rv = ((const ushort4*)rr)[t];
    float z[4];
    z[0] = xv.x + bf2f(rv.x);
    z[1] = xv.y + bf2f(rv.y);
    z[2] = xv.z + bf2f(rv.z);
    z[3] = xv.w + bf2f(rv.w);
    float s = z[0] + z[1] + z[2] + z[3];
#pragma unroll
    for (int off = 32; off > 0; off >>= 1) s += __shfl_down(s, off, 64);
    if ((t & 63) == 0) red[t >> 6] = s;
    __syncthreads();
    s = red[0] + red[1] + red[2] + red[3];
    float mean = s * (1.0f / (float)HDIM);

    float vs = 0.0f;
#pragma unroll
    for (int i = 0; i < 4; ++i) {
        float d = z[i] - mean;
        vs += d * d;
    }
#pragma unroll
    for (int off = 32; off > 0; off >>= 1) vs += __shfl_down(vs, off, 64);
    __syncthreads();
    if ((t & 63) == 0) red[t >> 6] = vs;
    __syncthreads();
    vs = red[0] + red[1] + red[2] + red[3];
    float inv = rsqrtf(vs * (1.0f / (float)HDIM) + 1e-12f);

    const float* g = ln + 4 * t;
    const float* bb = ln + HDIM + 4 * t;
    if (OUTF32) {
        float4 o;
        o.x = (z[0] - mean) * inv * g[0] + bb[0];
        o.y = (z[1] - mean) * inv * g[1] + bb[1];
        o.z = (z[2] - mean) * inv * g[2] + bb[2];
        o.w = (z[3] - mean) * inv * g[3] + bb[3];
        ((float4*)((float*)out + (size_t)row * HDIM))[t] = o;
    } else {
        ushort4 o;
        o.x = f2bf((z[0] - mean) * inv * g[0] + bb[0]);
        o.y = f2bf((z[1] - mean) * inv * g[1] + bb[1]);
        o.z = f2bf((z[2] - mean) * inv * g[2] + bb[2]);
        o.w = f2bf((z[3] - mean) * inv * g[3] + bb[3]);
        ((ushort4*)((unsigned short*)out + (size_t)row * HDIM))[t] = o;
    }
}

__global__ __launch_bounds__(256) void cvt_bf16_kernel(
    const float* __restrict__ in, unsigned short* __restrict__ out, int n4)
{
    int i = blockIdx.x * 256 + threadIdx.x;
    if (i < n4) {
        float4 v = ((const float4*)in)[i];
        ushort4 o;
        o.x = f2bf(v.x); o.y = f2bf(v.y); o.z = f2bf(v.z); o.w = f2bf(v.w);
        ((ushort4*)out)[i] = o;
    }
}

// ---------------------------------------------------------------------------
extern "C" void kernel_launch(void* const* d_in, const int* in_sizes, int n_in,
                              void* d_out, int out_size, void* d_ws, size_t ws_size,
                              hipStream_t stream)
{
    const float* in_hidden = (const float*)d_in[0];
    const float* enc_f     = (const float*)d_in[1];
    const int* attn_mask   = (const int*)d_in[2];
    const int* enc_attn_mask = (const int*)d_in[3];
    const float* sa_qkv_w  = (const float*)d_in[4];
    const float* sa_qkv_b  = (const float*)d_in[5];
    const float* sa_out_w  = (const float*)d_in[6];
    const float* sa_out_b  = (const float*)d_in[7];
    const float* sa_ln     = (const float*)d_in[8];
    const float* ca_qkv_w  = (const float*)d_in[9];
    const float* ca_qkv_b  = (const float*)d_in[10];
    const float* ca_out_w  = (const float*)d_in[11];
    const float* ca_out_b  = (const float*)d_in[12];
    const float* ca_ln     = (const float*)d_in[13];
    const float* o1_w      = (const float*)d_in[14];
    const float* o1_b      = (const float*)d_in[15];
    const float* o1_ln     = (const float*)d_in[16];
    const float* ffn_w     = (const float*)d_in[17];
    const float* ffn_b     = (const float*)d_in[18];
    const float* o2_w      = (const float*)d_in[19];
    const float* o2_b      = (const float*)d_in[20];
    const float* o2_ln     = (const float*)d_in[21];

    const size_t MH  = (size_t)MROWS * HDIM;   // 2,097,152
    const size_t Hsq = (size_t)HDIM * HDIM;    // 1,048,576
    const size_t HF  = (size_t)HDIM * FDIM;    // 4,194,304

    char* p = (char*)d_ws;
    unsigned short* wbf = (unsigned short*)p; p += (9 * Hsq + 2 * HF) * 2;  // ~34 MiB
    float* t2     = (float*)p; p += MH * 4;                                  // 8 MiB
    unsigned short* qb     = (unsigned short*)p; p += MH * 2;                // 4 MiB each
    unsigned short* kb     = (unsigned short*)p; p += MH * 2;
    unsigned short* vb     = (unsigned short*)p; p += MH * 2;
    unsigned short* ctx    = (unsigned short*)p; p += MH * 2;
    unsigned short* h      = (unsigned short*)p; p += MH * 2;
    unsigned short* enc_bf = (unsigned short*)p; p += MH * 2;
    unsigned short* attn1  = (unsigned short*)p; p += MH * 2;
    unsigned short* crossb = (unsigned short*)p; p += MH * 2;
    unsigned short* attn2  = (unsigned short*)p; p += MH * 2;
    unsigned short* tmp8b  = (unsigned short*)p; p += (size_t)MROWS * FDIM * 2; // 16 MiB

    unsigned short* w_saqkv = wbf;                 // [3072][1024]
    unsigned short* w_saout = wbf + 3 * Hsq;
    unsigned short* w_caqkv = wbf + 4 * Hsq;       // [3072][1024]
    unsigned short* w_caout = wbf + 7 * Hsq;
    unsigned short* w_o1    = wbf + 8 * Hsq;
    unsigned short* w_ffn   = wbf + 9 * Hsq;       // [4096][1024]
    unsigned short* w_o2    = wbf + 9 * Hsq + HF;  // [1024][4096]

    cvt_bf16_kernel<<<(MH / 4 + 255) / 256, 256, 0, stream>>>(in_hidden, h, MH / 4);
    cvt_bf16_kernel<<<(MH / 4 + 255) / 256, 256, 0, stream>>>(enc_f, enc_bf, MH / 4);

    for (int l = 0; l < LNUM; ++l) {
        // ---- all weight converts for this layer in one launch ----
        convtrans_all<<<4352, 256, 0, stream>>>(
            sa_qkv_w + (size_t)l * 3 * Hsq, sa_out_w + (size_t)l * Hsq,
            ca_qkv_w + (size_t)l * 3 * Hsq, ca_out_w + (size_t)l * Hsq,
            o1_w + (size_t)l * Hsq, ffn_w + (size_t)l * HF, o2_w + (size_t)l * HF,
            w_saqkv, w_saout, w_caqkv, w_caout, w_o1, w_ffn, w_o2);

        // ---- self attention ----
        mfma_gemm_qkv<64><<<dim3(MROWS / 64, 3072 / 64), 256, 0, stream>>>(
            h, h, w_saqkv, sa_qkv_b + (size_t)l * 3 * HDIM, qb, kb, vb, MROWS, HDIM);
        flash_attn<<<dim3(SDIM / 64, NHEAD, BDIM), 256, 0, stream>>>(
            qb, kb, vb, attn_mask, ctx);
        mfma_gemm<64, 64, false, false><<<dim3(MROWS / 64, HDIM / 64), 256, 0, stream>>>(
            ctx, w_saout, sa_out_b + (size_t)l * HDIM, t2, MROWS, HDIM, HDIM);
        ln_kernel<false><<<MROWS, 256, 0, stream>>>(t2, h, sa_ln + (size_t)l * 2 * HDIM, attn1);

        // ---- cross attention (residual = h; Q from h, KV from encoder) ----
        mfma_gemm_qkv<64><<<dim3(MROWS / 64, 3072 / 64), 256, 0, stream>>>(
            h, enc_bf, w_caqkv, ca_qkv_b + (size_t)l * 3 * HDIM, qb, kb, vb, MROWS, HDIM);
        flash_attn<<<dim3(SDIM / 64, NHEAD, BDIM), 256, 0, stream>>>(
            qb, kb, vb, enc_attn_mask, ctx);
        mfma_gemm<64, 64, false, false><<<dim3(MROWS / 64, HDIM / 64), 256, 0, stream>>>(
            ctx, w_caout, ca_out_b + (size_t)l * HDIM, t2, MROWS, HDIM, HDIM);
        ln_kernel<false><<<MROWS, 256, 0, stream>>>(t2, h, ca_ln + (size_t)l * 2 * HDIM, crossb);

        // ---- output_1 ----
        mfma_gemm<64, 64, false, false><<<dim3(MROWS / 64, HDIM / 64), 256, 0, stream>>>(
            attn1, w_o1, o1_b + (size_t)l * HDIM, t2, MROWS, HDIM, HDIM);
        ln_kernel<false><<<MROWS, 256, 0, stream>>>(t2, crossb, o1_ln + (size_t)l * 2 * HDIM, attn2);

        // ---- FFN ----
        mfma_gemm<64, 128, true, true><<<dim3(MROWS / 64, FDIM / 128), 256, 0, stream>>>(
            attn2, w_ffn, ffn_b + (size_t)l * FDIM, tmp8b, MROWS, FDIM, HDIM);
        mfma_gemm<64, 64, false, false><<<dim3(MROWS / 64, HDIM / 64), 256, 0, stream>>>(
            tmp8b, w_o2, o2_b + (size_t)l * HDIM, t2, MROWS, HDIM, FDIM);
        if (l == LNUM - 1)
            ln_kernel<true><<<MROWS, 256, 0, stream>>>(
                t2, attn2, o2_ln + (size_t)l * 2 * HDIM, (float*)d_out);
        else
            ln_kernel<false><<<MROWS, 256, 0, stream>>>(
                t2, attn2, o2_ln + (size_t)l * 2 * HDIM, h);
    }
}

// Round 4
// 1785.909 us; speedup vs baseline: 1.3611x; 1.1267x over previous
//
#include <hip/hip_runtime.h>

// ---------------------------------------------------------------------------
// T5 backbone forward, round 7:
//  - depth-3 LDS pipeline (3 buffers, loads issued 2 iters ahead,
//    steady-state s_waitcnt vmcnt(2*LPT)) -> covers ~900cy HBM latency that
//    depth-2 could not (round-6 post-mortem)
//  - SA and CA chains merged (independent until o1): one 6-way QKV GEMM
//    (N=6144, 3072 blocks), one flash launch (z=8), one batched out-proj
//    (z=2), one batched LN (z=2). 14 -> 10 dispatches/layer.
//  - keeps XOR chunk-swizzle (bank conflicts 0) + counted-vmcnt barriers
// ---------------------------------------------------------------------------

#define LNUM 6
#define HDIM 1024
#define NHEAD 16
#define DHEAD 64
#define BDIM 4
#define SDIM 512
#define FDIM 4096
#define MROWS (BDIM * SDIM)   // 2048
#define HSQ (HDIM * HDIM)

typedef __bf16 bf16_t;
typedef bf16_t bf16x8 __attribute__((ext_vector_type(8)));
typedef float f32x4 __attribute__((ext_vector_type(4)));

__device__ __forceinline__ float bf2f(unsigned short u) {
    union { unsigned int i; float f; } x;
    x.i = ((unsigned int)u) << 16;
    return x.f;
}

__device__ __forceinline__ unsigned short f2bf(float f) {
    union { float f; unsigned int i; } u;
    u.f = f;
    unsigned int x = u.i;
    unsigned int lsb = (x >> 16) & 1u;
    x += 0x7fffu + lsb;           // round-to-nearest-even
    return (unsigned short)(x >> 16);
}

// async global->LDS, 16 bytes per lane; lds dest = wave-uniform base + lane*16
__device__ __forceinline__ void async16(const unsigned short* g, unsigned short* l) {
    __builtin_amdgcn_global_load_lds(
        (const __attribute__((address_space(1))) unsigned int*)g,
        (__attribute__((address_space(3))) unsigned int*)l, 16, 0, 0);
}

template<int N>
__device__ __forceinline__ void s_wait_vmcnt() {
    asm volatile("s_waitcnt vmcnt(%0)" :: "n"(N) : "memory");
}

// ---------------------------------------------------------------------------
// MFMA GEMM: C[M,N] = A[M,K](bf16) @ BT[N,K](bf16)^T + bias(f32)
// BK=64, 256 threads (4 waves as 2x2). Depth-3 counted-vmcnt pipeline,
// XOR chunk-swizzled tiles.
// ---------------------------------------------------------------------------
template<int BM, int BN, bool GELU, bool OUTBF16>
__global__ __launch_bounds__(256) void mfma_gemm(
    const unsigned short* __restrict__ A,
    const unsigned short* __restrict__ BT,
    const float* __restrict__ bias,
    void* __restrict__ Cv,
    int M, int N, int K)
{
    constexpr int BK = 64;
    constexpr int MI = BM / 32;
    constexpr int NJ = BN / 32;
    constexpr int LPT = MI + NJ;   // global_load_lds per wave per tile

    __shared__ unsigned short As[3][BM][BK];
    __shared__ unsigned short Bs[3][BN][BK];

    const int t = threadIdx.x;
    const int w = t >> 6;
    const int lane = t & 63;
    const int quad = lane >> 4;
    const int cm = lane & 15;
    const int wrow = (w >> 1) * (BM / 2);
    const int wcol = (w & 1) * (BN / 2);
    const int row0 = blockIdx.x * BM;
    const int col0 = blockIdx.y * BN;

    f32x4 acc[MI][NJ] = {};

    const int lrow = lane >> 3;
    const int lcol = ((lane & 7) ^ lrow) * 8;   // pre-swizzled source chunk
    const int sw = cm & 15 & 7;

    auto stage = [&](int buf, int k0) {
#pragma unroll
        for (int j = 0; j < BM / 32; ++j) {
            int mb = w * (BM / 4) + j * 8;
            async16(A + (size_t)(row0 + mb + lrow) * K + k0 + lcol, &As[buf][mb][0]);
        }
#pragma unroll
        for (int j = 0; j < BN / 32; ++j) {
            int nb = w * (BN / 4) + j * 8;
            async16(BT + (size_t)(col0 + nb + lrow) * K + k0 + lcol, &Bs[buf][nb][0]);
        }
    };

    const int NT = K / BK;          // >= 16 for all call sites
    stage(0, 0);
    stage(1, BK);
    int c0 = 0, c1 = 1, c2 = 2;
    for (int ti = 0; ti < NT; ++ti) {
        if (ti + 2 < NT) {
            stage(c2, (ti + 2) * BK);        // issue 2 tiles ahead
            s_wait_vmcnt<2 * LPT>();         // tile ti landed (FIFO)
        } else if (ti + 1 < NT) {
            s_wait_vmcnt<LPT>();
        } else {
            s_wait_vmcnt<0>();
        }
        __builtin_amdgcn_s_barrier();        // all waves' tile-ti loads landed
        __builtin_amdgcn_sched_barrier(0);   // no ds_read hoists above this

#pragma unroll
        for (int kk = 0; kk < BK; kk += 32) {
            const int cc = kk >> 3;
            bf16x8 av[MI], bv[NJ];
#pragma unroll
            for (int i = 0; i < MI; ++i)
                av[i] = *(const bf16x8*)&As[c0][wrow + 16 * i + cm][((cc + quad) ^ sw) * 8];
#pragma unroll
            for (int j = 0; j < NJ; ++j)
                bv[j] = *(const bf16x8*)&Bs[c0][wcol + 16 * j + cm][((cc + quad) ^ sw) * 8];
#pragma unroll
            for (int i = 0; i < MI; ++i)
#pragma unroll
                for (int j = 0; j < NJ; ++j)
                    acc[i][j] = __builtin_amdgcn_mfma_f32_16x16x32_bf16(
                        av[i], bv[j], acc[i][j], 0, 0, 0);
        }

        __builtin_amdgcn_sched_barrier(0);   // no ds_read sinks below this
        __builtin_amdgcn_s_barrier();        // buf c0 free for overwrite
        int tmp = c0; c0 = c1; c1 = c2; c2 = tmp;
    }

#pragma unroll
    for (int j = 0; j < NJ; ++j) {
        int col = col0 + wcol + 16 * j + cm;
        float bb = bias[col];
#pragma unroll
        for (int i = 0; i < MI; ++i) {
#pragma unroll
            for (int r = 0; r < 4; ++r) {
                int row = row0 + wrow + 16 * i + quad * 4 + r;
                float c = acc[i][j][r] + bb;
                if (GELU) {
                    float u = 0.7978845608028654f * (c + 0.044715f * c * c * c);
                    c = 0.5f * c * (1.0f + tanhf(u));
                }
                if (OUTBF16)
                    ((unsigned short*)Cv)[(size_t)row * N + col] = f2bf(c);
                else
                    ((float*)Cv)[(size_t)row * N + col] = c;
            }
        }
    }
}

// ---------------------------------------------------------------------------
// 6-way QKV GEMM: SA (q,k,v from h) + CA (q from h; k,v from enc) in ONE
// launch. N = 6144 logical cols; sec = col0>>10 selects A, weights, dest.
// Depth-3 counted-vmcnt pipeline, BM=BN=64.
// ---------------------------------------------------------------------------
__global__ __launch_bounds__(256) void mfma_gemm_qkv6(
    const unsigned short* __restrict__ hA,
    const unsigned short* __restrict__ encA,
    const unsigned short* __restrict__ swq,   // SA qkv weights [3072][1024]
    const unsigned short* __restrict__ cwq,   // CA qkv weights [3072][1024]
    const float* __restrict__ sb, const float* __restrict__ cb,
    unsigned short* __restrict__ q1, unsigned short* __restrict__ k1,
    unsigned short* __restrict__ v1,
    unsigned short* __restrict__ q2, unsigned short* __restrict__ k2,
    unsigned short* __restrict__ v2,
    int M, int K)
{
    constexpr int BM = 64, BN = 64, BK = 64;
    constexpr int MI = 2, NJ = 2, LPT = 4;

    __shared__ unsigned short As[3][BM][BK];
    __shared__ unsigned short Bs[3][BN][BK];

    const int t = threadIdx.x;
    const int w = t >> 6;
    const int lane = t & 63;
    const int quad = lane >> 4;
    const int cm = lane & 15;
    const int wrow = (w >> 1) * 32;
    const int wcol = (w & 1) * 32;
    const int row0 = blockIdx.x * BM;
    const int col0 = blockIdx.y * BN;      // 0..6143

    const int sec = col0 >> 10;            // 0..5
    const unsigned short* __restrict__ A = (sec <= 3) ? hA : encA;
    const unsigned short* __restrict__ BT =
        (sec < 3) ? swq + (size_t)col0 * K : cwq + (size_t)(col0 - 3072) * K;
    const float* __restrict__ bias = (sec < 3) ? sb + col0 : cb + (col0 - 3072);

    f32x4 acc[MI][NJ] = {};

    const int lrow = lane >> 3;
    const int lcol = ((lane & 7) ^ lrow) * 8;
    const int sw = cm & 7;

    auto stage = [&](int buf, int k0) {
#pragma unroll
        for (int j = 0; j < 2; ++j) {
            int mb = w * 16 + j * 8;
            async16(A + (size_t)(row0 + mb + lrow) * K + k0 + lcol, &As[buf][mb][0]);
        }
#pragma unroll
        for (int j = 0; j < 2; ++j) {
            int nb = w * 16 + j * 8;
            async16(BT + (size_t)(nb + lrow) * K + k0 + lcol, &Bs[buf][nb][0]);
        }
    };

    const int NT = K / BK;
    stage(0, 0);
    stage(1, BK);
    int c0 = 0, c1 = 1, c2 = 2;
    for (int ti = 0; ti < NT; ++ti) {
        if (ti + 2 < NT) {
            stage(c2, (ti + 2) * BK);
            s_wait_vmcnt<2 * LPT>();
        } else if (ti + 1 < NT) {
            s_wait_vmcnt<LPT>();
        } else {
            s_wait_vmcnt<0>();
        }
        __builtin_amdgcn_s_barrier();
        __builtin_amdgcn_sched_barrier(0);

#pragma unroll
        for (int kk = 0; kk < 64; kk += 32) {
            const int cc = kk >> 3;
            bf16x8 av[MI], bv[NJ];
#pragma unroll
            for (int i = 0; i < MI; ++i)
                av[i] = *(const bf16x8*)&As[c0][wrow + 16 * i + cm][((cc + quad) ^ sw) * 8];
#pragma unroll
            for (int j = 0; j < NJ; ++j)
                bv[j] = *(const bf16x8*)&Bs[c0][wcol + 16 * j + cm][((cc + quad) ^ sw) * 8];
#pragma unroll
            for (int i = 0; i < MI; ++i)
#pragma unroll
                for (int j = 0; j < NJ; ++j)
                    acc[i][j] = __builtin_amdgcn_mfma_f32_16x16x32_bf16(
                        av[i], bv[j], acc[i][j], 0, 0, 0);
        }

        __builtin_amdgcn_sched_barrier(0);
        __builtin_amdgcn_s_barrier();
        int tmp = c0; c0 = c1; c1 = c2; c2 = tmp;
    }

    unsigned short* dst = sec == 0 ? q1 : sec == 1 ? k1 : sec == 2 ? v1
                        : sec == 3 ? q2 : sec == 4 ? k2 : v2;
    const int cbase = col0 & 1023;

#pragma unroll
    for (int j = 0; j < NJ; ++j) {
        float bb = bias[wcol + 16 * j + cm];
        int coll = cbase + wcol + 16 * j + cm;
#pragma unroll
        for (int i = 0; i < MI; ++i) {
#pragma unroll
            for (int r = 0; r < 4; ++r) {
                int row = row0 + wrow + 16 * i + quad * 4 + r;
                dst[(size_t)row * HDIM + coll] = f2bf(acc[i][j][r] + bb);
            }
        }
    }
}

// ---------------------------------------------------------------------------
// Batched (z=2) out-projection GEMM: z=0: C0=A0@B0^T+b0, z=1: C1=A1@B1^T+b1.
// f32 output. BM=BN=64, depth-3 pipeline.
// ---------------------------------------------------------------------------
__global__ __launch_bounds__(256) void mfma_gemm_out2(
    const unsigned short* __restrict__ A0, const unsigned short* __restrict__ B0,
    const float* __restrict__ b0, float* __restrict__ C0,
    const unsigned short* __restrict__ A1, const unsigned short* __restrict__ B1,
    const float* __restrict__ b1, float* __restrict__ C1,
    int M, int N, int K)
{
    constexpr int BM = 64, BN = 64, BK = 64;
    constexpr int MI = 2, NJ = 2, LPT = 4;

    __shared__ unsigned short As[3][BM][BK];
    __shared__ unsigned short Bs[3][BN][BK];

    const int z = blockIdx.z;
    const unsigned short* __restrict__ A  = z ? A1 : A0;
    const unsigned short* __restrict__ BT = z ? B1 : B0;
    const float* __restrict__ bias = z ? b1 : b0;
    float* __restrict__ Cv = z ? C1 : C0;

    const int t = threadIdx.x;
    const int w = t >> 6;
    const int lane = t & 63;
    const int quad = lane >> 4;
    const int cm = lane & 15;
    const int wrow = (w >> 1) * 32;
    const int wcol = (w & 1) * 32;
    const int row0 = blockIdx.x * BM;
    const int col0 = blockIdx.y * BN;

    f32x4 acc[MI][NJ] = {};

    const int lrow = lane >> 3;
    const int lcol = ((lane & 7) ^ lrow) * 8;
    const int sw = cm & 7;

    auto stage = [&](int buf, int k0) {
#pragma unroll
        for (int j = 0; j < 2; ++j) {
            int mb = w * 16 + j * 8;
            async16(A + (size_t)(row0 + mb + lrow) * K + k0 + lcol, &As[buf][mb][0]);
        }
#pragma unroll
        for (int j = 0; j < 2; ++j) {
            int nb = w * 16 + j * 8;
            async16(BT + (size_t)(col0 + nb + lrow) * K + k0 + lcol, &Bs[buf][nb][0]);
        }
    };

    const int NT = K / BK;
    stage(0, 0);
    stage(1, BK);
    int c0 = 0, c1 = 1, c2 = 2;
    for (int ti = 0; ti < NT; ++ti) {
        if (ti + 2 < NT) {
            stage(c2, (ti + 2) * BK);
            s_wait_vmcnt<2 * LPT>();
        } else if (ti + 1 < NT) {
            s_wait_vmcnt<LPT>();
        } else {
            s_wait_vmcnt<0>();
        }
        __builtin_amdgcn_s_barrier();
        __builtin_amdgcn_sched_barrier(0);

#pragma unroll
        for (int kk = 0; kk < 64; kk += 32) {
            const int cc = kk >> 3;
            bf16x8 av[MI], bv[NJ];
#pragma unroll
            for (int i = 0; i < MI; ++i)
                av[i] = *(const bf16x8*)&As[c0][wrow + 16 * i + cm][((cc + quad) ^ sw) * 8];
#pragma unroll
            for (int j = 0; j < NJ; ++j)
                bv[j] = *(const bf16x8*)&Bs[c0][wcol + 16 * j + cm][((cc + quad) ^ sw) * 8];
#pragma unroll
            for (int i = 0; i < MI; ++i)
#pragma unroll
                for (int j = 0; j < NJ; ++j)
                    acc[i][j] = __builtin_amdgcn_mfma_f32_16x16x32_bf16(
                        av[i], bv[j], acc[i][j], 0, 0, 0);
        }

        __builtin_amdgcn_sched_barrier(0);
        __builtin_amdgcn_s_barrier();
        int tmp = c0; c0 = c1; c1 = c2; c2 = tmp;
    }

#pragma unroll
    for (int j = 0; j < NJ; ++j) {
        int col = col0 + wcol + 16 * j + cm;
        float bb = bias[col];
#pragma unroll
        for (int i = 0; i < MI; ++i) {
#pragma unroll
            for (int r = 0; r < 4; ++r) {
                int row = row0 + wrow + 16 * i + quad * 4 + r;
                Cv[(size_t)row * N + col] = acc[i][j][r] + bb;
            }
        }
    }
}

// ---------------------------------------------------------------------------
// Flash attention, SA+CA merged: grid (S/64, NH, 2*B). z = b + B*which.
// Each wave owns 16 q-rows; KV tiles of 64; online softmax; ctx bf16 out.
// ---------------------------------------------------------------------------
__global__ __launch_bounds__(256) void flash_attn(
    const unsigned short* __restrict__ q1, const unsigned short* __restrict__ k1,
    const unsigned short* __restrict__ v1,
    const unsigned short* __restrict__ q2, const unsigned short* __restrict__ k2,
    const unsigned short* __restrict__ v2,
    const int* __restrict__ mask1, const int* __restrict__ mask2,
    unsigned short* __restrict__ ctx1, unsigned short* __restrict__ ctx2)
{
    __shared__ unsigned short Qs[64][64];
    __shared__ unsigned short Ks[64][64];
    __shared__ unsigned short Vs[64][72];      // transposed: Vs[d][j] (padded)
    __shared__ unsigned short Ps[4][16][72];   // per-wave P tile [m][j] (padded)

    const int t = threadIdx.x;
    const int w = t >> 6;
    const int lane = t & 63;
    const int quad = lane >> 4;
    const int cm = lane & 15;
    const int sw = cm & 7;

    const int q0 = blockIdx.x * 64;
    const int h = blockIdx.y;
    const int zz = blockIdx.z;
    const int b = zz & (BDIM - 1);
    const int which = zz >> 2;
    const unsigned short* __restrict__ q = which ? q2 : q1;
    const unsigned short* __restrict__ k = which ? k2 : k1;
    const unsigned short* __restrict__ v = which ? v2 : v1;
    const int* __restrict__ mask = which ? mask2 : mask1;
    unsigned short* __restrict__ ctx = which ? ctx2 : ctx1;

    const size_t rowbase = (size_t)b * SDIM;
    const int hoff = h * DHEAD;

    // stage Q tile (64x64), swizzled chunks
#pragma unroll
    for (int l = 0; l < 2; ++l) {
        int idx = t + l * 256;           // 0..511
        int r = idx >> 3;                // 0..63
        int c = idx & 7;                 // logical chunk
        *(uint4*)&Qs[r][((c ^ (r & 7)) * 8)] =
            *(const uint4*)(q + (rowbase + q0 + r) * HDIM + hoff + c * 8);
    }

    float m_prev[4] = {-1e30f, -1e30f, -1e30f, -1e30f};
    float l_sum[4] = {0.0f, 0.0f, 0.0f, 0.0f};
    f32x4 oacc[4] = {};

    for (int j0 = 0; j0 < SDIM; j0 += 64) {
        __syncthreads();   // previous iteration's compute done before restaging
#pragma unroll
        for (int l = 0; l < 2; ++l) {
            int idx = t + l * 256;
            int r = idx >> 3;
            int c = idx & 7;
            *(uint4*)&Ks[r][((c ^ (r & 7)) * 8)] =
                *(const uint4*)(k + (rowbase + j0 + r) * HDIM + hoff + c * 8);
        }
#pragma unroll
        for (int l = 0; l < 4; ++l) {
            int idx = t + l * 256;       // 0..1023
            int jj = idx >> 4;           // 0..63
            int d0 = (idx & 15) * 4;
            ushort4 vv = *(const ushort4*)(v + (rowbase + j0 + jj) * HDIM + hoff + d0);
            Vs[d0 + 0][jj] = vv.x;
            Vs[d0 + 1][jj] = vv.y;
            Vs[d0 + 2][jj] = vv.z;
            Vs[d0 + 3][jj] = vv.w;
        }
        __syncthreads();

        // S = Q K^T for this wave's 16 rows x 64 kv cols
        f32x4 sacc[4] = {};
#pragma unroll
        for (int kk = 0; kk < 64; kk += 32) {
            const int cc = kk >> 3;
            bf16x8 av = *(const bf16x8*)&Qs[w * 16 + cm][((cc + quad) ^ sw) * 8];
#pragma unroll
            for (int j2 = 0; j2 < 4; ++j2) {
                bf16x8 bv = *(const bf16x8*)&Ks[j2 * 16 + cm][((cc + quad) ^ sw) * 8];
                sacc[j2] = __builtin_amdgcn_mfma_f32_16x16x32_bf16(av, bv, sacc[j2], 0, 0, 0);
            }
        }

        float madd[4];
#pragma unroll
        for (int j2 = 0; j2 < 4; ++j2)
            madd[j2] = (1.0f - (float)mask[b * SDIM + j0 + j2 * 16 + cm]) * -10000.0f;

#pragma unroll
        for (int r = 0; r < 4; ++r) {
            float s0 = sacc[0][r] * 0.125f + madd[0];
            float s1 = sacc[1][r] * 0.125f + madd[1];
            float s2 = sacc[2][r] * 0.125f + madd[2];
            float s3 = sacc[3][r] * 0.125f + madd[3];
            float rm = fmaxf(fmaxf(s0, s1), fmaxf(s2, s3));
#pragma unroll
            for (int mo = 1; mo < 16; mo <<= 1)
                rm = fmaxf(rm, __shfl_xor(rm, mo, 64));
            float new_m = fmaxf(m_prev[r], rm);
            float alpha = __expf(m_prev[r] - new_m);
            m_prev[r] = new_m;
            float p0 = __expf(s0 - new_m);
            float p1 = __expf(s1 - new_m);
            float p2 = __expf(s2 - new_m);
            float p3 = __expf(s3 - new_m);
            float rs = p0 + p1 + p2 + p3;
#pragma unroll
            for (int mo = 1; mo < 16; mo <<= 1)
                rs += __shfl_xor(rs, mo, 64);
            l_sum[r] = l_sum[r] * alpha + rs;
#pragma unroll
            for (int d2 = 0; d2 < 4; ++d2)
                oacc[d2][r] *= alpha;
            int prow = quad * 4 + r;
            Ps[w][prow][0 * 16 + cm] = f2bf(p0);
            Ps[w][prow][1 * 16 + cm] = f2bf(p1);
            Ps[w][prow][2 * 16 + cm] = f2bf(p2);
            Ps[w][prow][3 * 16 + cm] = f2bf(p3);
        }

        // O += P V
#pragma unroll
        for (int kk = 0; kk < 64; kk += 32) {
            bf16x8 pa = *(const bf16x8*)&Ps[w][cm][kk + quad * 8];
#pragma unroll
            for (int d2 = 0; d2 < 4; ++d2) {
                bf16x8 bv = *(const bf16x8*)&Vs[d2 * 16 + cm][kk + quad * 8];
                oacc[d2] = __builtin_amdgcn_mfma_f32_16x16x32_bf16(pa, bv, oacc[d2], 0, 0, 0);
            }
        }
    }

#pragma unroll
    for (int r = 0; r < 4; ++r) {
        float inv = 1.0f / l_sum[r];
        int row = q0 + w * 16 + quad * 4 + r;
#pragma unroll
        for (int d2 = 0; d2 < 4; ++d2) {
            ctx[(rowbase + row) * HDIM + hoff + d2 * 16 + cm] = f2bf(oacc[d2][r] * inv);
        }
    }
}

// ---------------------------------------------------------------------------
// Fused weight convert + transpose for ONE layer (7 matrices, 4352 tiles).
// fp32 [K][N] -> bf16 [N][K], 64x64 tiles.
// ---------------------------------------------------------------------------
__global__ __launch_bounds__(256) void convtrans_all(
    const float* __restrict__ sqkv, const float* __restrict__ sout,
    const float* __restrict__ cqkv, const float* __restrict__ cout,
    const float* __restrict__ o1w,  const float* __restrict__ ffnw,
    const float* __restrict__ o2w,
    unsigned short* __restrict__ dq,  unsigned short* __restrict__ dso,
    unsigned short* __restrict__ dcq, unsigned short* __restrict__ dco,
    unsigned short* __restrict__ do1, unsigned short* __restrict__ dffn,
    unsigned short* __restrict__ do2)
{
    __shared__ unsigned short tile[64][72];
    const int bid = blockIdx.x;
    const float* src;
    unsigned short* dst;
    int K, N, tt;
    if (bid < 2304) {
        int m = bid >> 8;        // 0..8
        tt = bid & 255;
        K = HDIM; N = HDIM;
        if (m < 3)      { src = sqkv + (size_t)m * HSQ;       dst = dq  + (size_t)m * HSQ; }
        else if (m < 6) { src = cqkv + (size_t)(m - 3) * HSQ; dst = dcq + (size_t)(m - 3) * HSQ; }
        else if (m == 6){ src = sout; dst = dso; }
        else if (m == 7){ src = cout; dst = dco; }
        else            { src = o1w;  dst = do1; }
    } else if (bid < 3328) {
        tt = bid - 2304; K = HDIM; N = FDIM; src = ffnw; dst = dffn;
    } else {
        tt = bid - 3328; K = FDIM; N = HDIM; src = o2w; dst = do2;
    }
    const int tn = N >> 6;
    const int n0 = (tt % tn) * 64;
    const int k0 = (tt / tn) * 64;
    const int t = threadIdx.x;
#pragma unroll
    for (int l = 0; l < 4; ++l) {
        int idx = t + l * 256;
        int kk = idx >> 4;
        int nn = (idx & 15) * 4;
        float4 v = *(const float4*)(src + (size_t)(k0 + kk) * N + n0 + nn);
        tile[nn + 0][kk] = f2bf(v.x);
        tile[nn + 1][kk] = f2bf(v.y);
        tile[nn + 2][kk] = f2bf(v.z);
        tile[nn + 3][kk] = f2bf(v.w);
    }
    __syncthreads();
#pragma unroll
    for (int l = 0; l < 2; ++l) {
        int c = t + l * 256;
        int nn = c >> 3;
        int kk = (c & 7) * 8;
        *(uint4*)(dst + (size_t)(n0 + nn) * K + k0 + kk) = *(const uint4*)&tile[nn][kk];
    }
}

// ---------------------------------------------------------------------------
// Fused residual + LayerNorm: out = LN(x(f32) + resid(bf16)) * g + b
// ---------------------------------------------------------------------------
template<bool OUTF32>
__global__ __launch_bounds__(256) void ln_kernel(
    const float* __restrict__ x, const unsigned short* __restrict__ resid,
    const float* __restrict__ ln, void* __restrict__ out)
{
    const int row = blockIdx.x;
    const float* xr = x + (size_t)row * HDIM;
    const unsigned short* rr = resid + (size_t)row * HDIM;
    const int t = threadIdx.x;
    __shared__ float red[4];

    float4 xv = ((const float4*)xr)[t];
    ushort4 rv = ((const ushort4*)rr)[t];
    float z[4];
    z[0] = xv.x + bf2f(rv.x);
    z[1] = xv.y + bf2f(rv.y);
    z[2] = xv.z + bf2f(rv.z);
    z[3] = xv.w + bf2f(rv.w);
    float s = z[0] + z[1] + z[2] + z[3];
#pragma unroll
    for (int off = 32; off > 0; off >>= 1) s += __shfl_down(s, off, 64);
    if ((t & 63) == 0) red[t >> 6] = s;
    __syncthreads();
    s = red[0] + red[1] + red[2] + red[3];
    float mean = s * (1.0f / (float)HDIM);

    float vs = 0.0f;
#pragma unroll
    for (int i = 0; i < 4; ++i) {
        float d = z[i] - mean;
        vs += d * d;
    }
#pragma unroll
    for (int off = 32; off > 0; off >>= 1) vs += __shfl_down(vs, off, 64);
    __syncthreads();
    if ((t & 63) == 0) red[t >> 6] = vs;
    __syncthreads();
    vs = red[0] + red[1] + red[2] + red[3];
    float inv = rsqrtf(vs * (1.0f / (float)HDIM) + 1e-12f);

    const float* g = ln + 4 * t;
    const float* bb = ln + HDIM + 4 * t;
    if (OUTF32) {
        float4 o;
        o.x = (z[0] - mean) * inv * g[0] + bb[0];
        o.y = (z[1] - mean) * inv * g[1] + bb[1];
        o.z = (z[2] - mean) * inv * g[2] + bb[2];
        o.w = (z[3] - mean) * inv * g[3] + bb[3];
        ((float4*)((float*)out + (size_t)row * HDIM))[t] = o;
    } else {
        ushort4 o;
        o.x = f2bf((z[0] - mean) * inv * g[0] + bb[0]);
        o.y = f2bf((z[1] - mean) * inv * g[1] + bb[1]);
        o.z = f2bf((z[2] - mean) * inv * g[2] + bb[2]);
        o.w = f2bf((z[3] - mean) * inv * g[3] + bb[3]);
        ((ushort4*)((unsigned short*)out + (size_t)row * HDIM))[t] = o;
    }
}

// Batched z=2 LN (both residual = resid): z=0: LN(xa+resid)->outa, z=1: xb->outb
__global__ __launch_bounds__(256) void ln2_kernel(
    const float* __restrict__ xa, const float* __restrict__ xb,
    const unsigned short* __restrict__ resid,
    const float* __restrict__ lna, const float* __restrict__ lnb,
    unsigned short* __restrict__ outa, unsigned short* __restrict__ outb)
{
    const int row = blockIdx.x;
    const int z2 = blockIdx.y;
    const float* x = z2 ? xb : xa;
    const float* ln = z2 ? lnb : lna;
    unsigned short* out = z2 ? outb : outa;

    const float* xr = x + (size_t)row * HDIM;
    const unsigned short* rr = resid + (size_t)row * HDIM;
    const int t = threadIdx.x;
    __shared__ float red[4];

    float4 xv = ((const float4*)xr)[t];
    ushort4 rv = ((const ushort4*)rr)[t];
    float z[4];
    z[0] = xv.x + bf2f(rv.x);
    z[1] = xv.y + bf2f(rv.y);
    z[2] = xv.z + bf2f(rv.z);
    z[3] = xv.w + bf2f(rv.w);
    float s = z[0] + z[1] + z[2] + z[3];
#pragma unroll
    for (int off = 32; off > 0; off >>= 1) s += __shfl_down(s, off, 64);
    if ((t & 63) == 0) red[t >> 6] = s;
    __syncthreads();
    s = red[0] + red[1] + red[2] + red[3];
    float mean = s * (1.0f / (float)HDIM);

    float vs = 0.0f;
#pragma unroll
    for (int i = 0; i < 4; ++i) {
        float d = z[i] - mean;
        vs += d * d;
    }
#pragma unroll
    for (int off = 32; off > 0; off >>= 1) vs += __shfl_down(vs, off, 64);
    __syncthreads();
    if ((t & 63) == 0) red[t >> 6] = vs;
    __syncthreads();
    vs = red[0] + red[1] + red[2] + red[3];
    float inv = rsqrtf(vs * (1.0f / (float)HDIM) + 1e-12f);

    const float* g = ln + 4 * t;
    const float* bb = ln + HDIM + 4 * t;
    ushort4 o;
    o.x = f2bf((z[0] - mean) * inv * g[0] + bb[0]);
    o.y = f2bf((z[1] - mean) * inv * g[1] + bb[1]);
    o.z = f2bf((z[2] - mean) * inv * g[2] + bb[2]);
    o.w = f2bf((z[3] - mean) * inv * g[3] + bb[3]);
    ((ushort4*)(out + (size_t)row * HDIM))[t] = o;
}

__global__ __launch_bounds__(256) void cvt_bf16_kernel(
    const float* __restrict__ in, unsigned short* __restrict__ out, int n4)
{
    int i = blockIdx.x * 256 + threadIdx.x;
    if (i < n4) {
        float4 v = ((const float4*)in)[i];
        ushort4 o;
        o.x = f2bf(v.x); o.y = f2bf(v.y); o.z = f2bf(v.z); o.w = f2bf(v.w);
        ((ushort4*)out)[i] = o;
    }
}

// ---------------------------------------------------------------------------
extern "C" void kernel_launch(void* const* d_in, const int* in_sizes, int n_in,
                              void* d_out, int out_size, void* d_ws, size_t ws_size,
                              hipStream_t stream)
{
    const float* in_hidden = (const float*)d_in[0];
    const float* enc_f     = (const float*)d_in[1];
    const int* attn_mask   = (const int*)d_in[2];
    const int* enc_attn_mask = (const int*)d_in[3];
    const float* sa_qkv_w  = (const float*)d_in[4];
    const float* sa_qkv_b  = (const float*)d_in[5];
    const float* sa_out_w  = (const float*)d_in[6];
    const float* sa_out_b  = (const float*)d_in[7];
    const float* sa_ln     = (const float*)d_in[8];
    const float* ca_qkv_w  = (const float*)d_in[9];
    const float* ca_qkv_b  = (const float*)d_in[10];
    const float* ca_out_w  = (const float*)d_in[11];
    const float* ca_out_b  = (const float*)d_in[12];
    const float* ca_ln     = (const float*)d_in[13];
    const float* o1_w      = (const float*)d_in[14];
    const float* o1_b      = (const float*)d_in[15];
    const float* o1_ln     = (const float*)d_in[16];
    const float* ffn_w     = (const float*)d_in[17];
    const float* ffn_b     = (const float*)d_in[18];
    const float* o2_w      = (const float*)d_in[19];
    const float* o2_b      = (const float*)d_in[20];
    const float* o2_ln     = (const float*)d_in[21];

    const size_t MH  = (size_t)MROWS * HDIM;   // 2,097,152
    const size_t Hsq = (size_t)HDIM * HDIM;    // 1,048,576
    const size_t HF  = (size_t)HDIM * FDIM;    // 4,194,304

    char* p = (char*)d_ws;
    unsigned short* wbf = (unsigned short*)p; p += (9 * Hsq + 2 * HF) * 2;  // ~34 MiB
    float* t2a    = (float*)p; p += MH * 4;                                  // 8 MiB
    float* t2b    = (float*)p; p += MH * 4;                                  // 8 MiB
    unsigned short* qb     = (unsigned short*)p; p += MH * 2;                // 4 MiB each
    unsigned short* kb     = (unsigned short*)p; p += MH * 2;
    unsigned short* vb     = (unsigned short*)p; p += MH * 2;
    unsigned short* qb2    = (unsigned short*)p; p += MH * 2;
    unsigned short* kb2    = (unsigned short*)p; p += MH * 2;
    unsigned short* vb2    = (unsigned short*)p; p += MH * 2;
    unsigned short* ctx    = (unsigned short*)p; p += MH * 2;
    unsigned short* ctx2   = (unsigned short*)p; p += MH * 2;
    unsigned short* h      = (unsigned short*)p; p += MH * 2;
    unsigned short* enc_bf = (unsigned short*)p; p += MH * 2;
    unsigned short* attn1  = (unsigned short*)p; p += MH * 2;
    unsigned short* crossb = (unsigned short*)p; p += MH * 2;
    unsigned short* attn2  = (unsigned short*)p; p += MH * 2;
    unsigned short* tmp8b  = (unsigned short*)p; p += (size_t)MROWS * FDIM * 2; // 16 MiB

    unsigned short* w_saqkv = wbf;                 // [3072][1024]
    unsigned short* w_saout = wbf + 3 * Hsq;
    unsigned short* w_caqkv = wbf + 4 * Hsq;       // [3072][1024]
    unsigned short* w_caout = wbf + 7 * Hsq;
    unsigned short* w_o1    = wbf + 8 * Hsq;
    unsigned short* w_ffn   = wbf + 9 * Hsq;       // [4096][1024]
    unsigned short* w_o2    = wbf + 9 * Hsq + HF;  // [1024][4096]

    cvt_bf16_kernel<<<(MH / 4 + 255) / 256, 256, 0, stream>>>(in_hidden, h, MH / 4);
    cvt_bf16_kernel<<<(MH / 4 + 255) / 256, 256, 0, stream>>>(enc_f, enc_bf, MH / 4);

    for (int l = 0; l < LNUM; ++l) {
        // ---- all weight converts for this layer in one launch ----
        convtrans_all<<<4352, 256, 0, stream>>>(
            sa_qkv_w + (size_t)l * 3 * Hsq, sa_out_w + (size_t)l * Hsq,
            ca_qkv_w + (size_t)l * 3 * Hsq, ca_out_w + (size_t)l * Hsq,
            o1_w + (size_t)l * Hsq, ffn_w + (size_t)l * HF, o2_w + (size_t)l * HF,
            w_saqkv, w_saout, w_caqkv, w_caout, w_o1, w_ffn, w_o2);

        // ---- SA + CA QKV projections, one launch (N=6144) ----
        mfma_gemm_qkv6<<<dim3(MROWS / 64, 6144 / 64), 256, 0, stream>>>(
            h, enc_bf, w_saqkv, w_caqkv,
            sa_qkv_b + (size_t)l * 3 * HDIM, ca_qkv_b + (size_t)l * 3 * HDIM,
            qb, kb, vb, qb2, kb2, vb2, MROWS, HDIM);

        // ---- SA + CA flash attention, one launch ----
        flash_attn<<<dim3(SDIM / 64, NHEAD, 2 * BDIM), 256, 0, stream>>>(
            qb, kb, vb, qb2, kb2, vb2, attn_mask, enc_attn_mask, ctx, ctx2);

        // ---- SA + CA output projections, one launch (z=2) ----
        mfma_gemm_out2<<<dim3(MROWS / 64, HDIM / 64, 2), 256, 0, stream>>>(
            ctx, w_saout, sa_out_b + (size_t)l * HDIM, t2a,
            ctx2, w_caout, ca_out_b + (size_t)l * HDIM, t2b,
            MROWS, HDIM, HDIM);

        // ---- both LNs (residual = h), one launch (z=2) ----
        ln2_kernel<<<dim3(MROWS, 2), 256, 0, stream>>>(
            t2a, t2b, h, sa_ln + (size_t)l * 2 * HDIM, ca_ln + (size_t)l * 2 * HDIM,
            attn1, crossb);

        // ---- output_1 ----
        mfma_gemm<64, 64, false, false><<<dim3(MROWS / 64, HDIM / 64), 256, 0, stream>>>(
            attn1, w_o1, o1_b + (size_t)l * HDIM, t2a, MROWS, HDIM, HDIM);
        ln_kernel<false><<<MROWS, 256, 0, stream>>>(t2a, crossb, o1_ln + (size_t)l * 2 * HDIM, attn2);

        // ---- FFN ----
        mfma_gemm<64, 128, true, true><<<dim3(MROWS / 64, FDIM / 128), 256, 0, stream>>>(
            attn2, w_ffn, ffn_b + (size_t)l * FDIM, tmp8b, MROWS, FDIM, HDIM);
        mfma_gemm<64, 64, false, false><<<dim3(MROWS / 64, HDIM / 64), 256, 0, stream>>>(
            tmp8b, w_o2, o2_b + (size_t)l * HDIM, t2a, MROWS, HDIM, FDIM);
        if (l == LNUM - 1)
            ln_kernel<true><<<MROWS, 256, 0, stream>>>(
                t2a, attn2, o2_ln + (size_t)l * 2 * HDIM, (float*)d_out);
        else
            ln_kernel<false><<<MROWS, 256, 0, stream>>>(
                t2a, attn2, o2_ln + (size_t)l * 2 * HDIM, h);
    }
}

// Round 5
// 1780.000 us; speedup vs baseline: 1.3657x; 1.0033x over previous
//
#include <hip/hip_runtime.h>

// ---------------------------------------------------------------------------
// T5 backbone forward, round 8:
//  - ALL GEMMs on one shared core: 128x128 tile, 512 thr (8 waves as 2x4,
//    wave-tile 64x32 -> 16 MFMA : 12 ds_read per K-step, vs 8:8 at 64x64),
//    depth-3 counted-vmcnt pipeline, XOR chunk-swizzle, LDS 96KB
//  - N=1024 GEMMs (o1, ffn2) use split-K2 (grid 256) with partial sums
//    combined inside ln3 (LN(xa+xb+resid)) -> no grid underfill, no extra pass
//  - SA+CA merge, flash z=8, fused convtrans, ln2 kept from round 7
// ---------------------------------------------------------------------------

#define LNUM 6
#define HDIM 1024
#define NHEAD 16
#define DHEAD 64
#define BDIM 4
#define SDIM 512
#define FDIM 4096
#define MROWS (BDIM * SDIM)   // 2048
#define HSQ (HDIM * HDIM)

typedef __bf16 bf16_t;
typedef bf16_t bf16x8 __attribute__((ext_vector_type(8)));
typedef float f32x4 __attribute__((ext_vector_type(4)));

__device__ __forceinline__ float bf2f(unsigned short u) {
    union { unsigned int i; float f; } x;
    x.i = ((unsigned int)u) << 16;
    return x.f;
}

__device__ __forceinline__ unsigned short f2bf(float f) {
    union { float f; unsigned int i; } u;
    u.f = f;
    unsigned int x = u.i;
    unsigned int lsb = (x >> 16) & 1u;
    x += 0x7fffu + lsb;           // round-to-nearest-even
    return (unsigned short)(x >> 16);
}

// async global->LDS, 16 bytes per lane; lds dest = wave-uniform base + lane*16
__device__ __forceinline__ void async16(const unsigned short* g, unsigned short* l) {
    __builtin_amdgcn_global_load_lds(
        (const __attribute__((address_space(1))) unsigned int*)g,
        (__attribute__((address_space(3))) unsigned int*)l, 16, 0, 0);
}

template<int N>
__device__ __forceinline__ void s_wait_vmcnt() {
    asm volatile("s_waitcnt vmcnt(%0)" :: "n"(N) : "memory");
}

// ---------------------------------------------------------------------------
// Shared GEMM core: 128x128 tile, 512 threads (8 waves as 2 rows x 4 cols,
// wave-tile 64x32: MI=4, NJ=2). Depth-3 counted-vmcnt pipeline.
// Abase / Bbase are pre-offset to the tile's first row ([128][K] views).
// Computes acc over k in [kbeg, kend) (elements, multiple of 64).
// ---------------------------------------------------------------------------
__device__ __forceinline__ void gemm128_core(
    const unsigned short* __restrict__ Abase,
    const unsigned short* __restrict__ Bbase,
    int K, int kbeg, int kend,
    unsigned short (&As)[3][128][64], unsigned short (&Bs)[3][128][64],
    f32x4 (&acc)[4][2])
{
    const int t = threadIdx.x;
    const int w = t >> 6;                 // 0..7
    const int lane = t & 63;
    const int quad = lane >> 4;
    const int cm = lane & 15;
    const int wrow = (w >> 2) * 64;       // 2 wave-rows
    const int wcol = (w & 3) * 32;        // 4 wave-cols

    const int lrow = lane >> 3;           // 0..7
    const int lcol = ((lane & 7) ^ lrow) * 8;   // pre-swizzled source chunk
    const int sw = cm & 7;

    auto stage = [&](int buf, int k0) {
#pragma unroll
        for (int j = 0; j < 2; ++j) {
            int rb = w * 16 + j * 8;      // 8 waves x 16 rows = 128
            async16(Abase + (size_t)(rb + lrow) * K + k0 + lcol, &As[buf][rb][0]);
            async16(Bbase + (size_t)(rb + lrow) * K + k0 + lcol, &Bs[buf][rb][0]);
        }
    };

    const int NT = (kend - kbeg) / 64;    // >= 8 at all call sites
    stage(0, kbeg);
    stage(1, kbeg + 64);
    int c0 = 0, c1 = 1, c2 = 2;
    for (int ti = 0; ti < NT; ++ti) {
        if (ti + 2 < NT) {
            stage(c2, kbeg + (ti + 2) * 64);   // issue 2 tiles ahead
            s_wait_vmcnt<8>();                 // 2*LPT: tile ti landed (FIFO)
        } else if (ti + 1 < NT) {
            s_wait_vmcnt<4>();
        } else {
            s_wait_vmcnt<0>();
        }
        __builtin_amdgcn_s_barrier();          // all waves' tile-ti loads landed
        __builtin_amdgcn_sched_barrier(0);     // no ds_read hoists above

#pragma unroll
        for (int kk = 0; kk < 64; kk += 32) {
            const int cc = kk >> 3;
            bf16x8 av[4], bv[2];
#pragma unroll
            for (int i = 0; i < 4; ++i)
                av[i] = *(const bf16x8*)&As[c0][wrow + 16 * i + cm][((cc + quad) ^ sw) * 8];
#pragma unroll
            for (int j = 0; j < 2; ++j)
                bv[j] = *(const bf16x8*)&Bs[c0][wcol + 16 * j + cm][((cc + quad) ^ sw) * 8];
#pragma unroll
            for (int i = 0; i < 4; ++i)
#pragma unroll
                for (int j = 0; j < 2; ++j)
                    acc[i][j] = __builtin_amdgcn_mfma_f32_16x16x32_bf16(
                        av[i], bv[j], acc[i][j], 0, 0, 0);
        }

        __builtin_amdgcn_sched_barrier(0);     // no ds_read sinks below
        __builtin_amdgcn_s_barrier();          // buf c0 free for overwrite
        int tmp = c0; c0 = c1; c1 = c2; c2 = tmp;
    }
}

// ---------------------------------------------------------------------------
// Generic GEMM: C[M,N] = A @ BT^T + bias.  (ffn1 uses GELU+bf16 out)
// ---------------------------------------------------------------------------
template<bool GELU, bool OUTBF16>
__global__ __launch_bounds__(512) void gemm128(
    const unsigned short* __restrict__ A,
    const unsigned short* __restrict__ BT,
    const float* __restrict__ bias,
    void* __restrict__ Cv,
    int M, int N, int K)
{
    __shared__ unsigned short As[3][128][64];
    __shared__ unsigned short Bs[3][128][64];

    const int row0 = blockIdx.x * 128;
    const int col0 = blockIdx.y * 128;
    const int t = threadIdx.x;
    const int w = t >> 6;
    const int lane = t & 63;
    const int quad = lane >> 4;
    const int cm = lane & 15;
    const int wrow = (w >> 2) * 64;
    const int wcol = (w & 3) * 32;

    f32x4 acc[4][2] = {};
    gemm128_core(A + (size_t)row0 * K, BT + (size_t)col0 * K, K, 0, K, As, Bs, acc);

#pragma unroll
    for (int j = 0; j < 2; ++j) {
        int col = col0 + wcol + 16 * j + cm;
        float bb = bias[col];
#pragma unroll
        for (int i = 0; i < 4; ++i) {
#pragma unroll
            for (int r = 0; r < 4; ++r) {
                int row = row0 + wrow + 16 * i + quad * 4 + r;
                float c = acc[i][j][r] + bb;
                if (GELU) {
                    float u = 0.7978845608028654f * (c + 0.044715f * c * c * c);
                    c = 0.5f * c * (1.0f + tanhf(u));
                }
                if (OUTBF16)
                    ((unsigned short*)Cv)[(size_t)row * N + col] = f2bf(c);
                else
                    ((float*)Cv)[(size_t)row * N + col] = c;
            }
        }
    }
}

// ---------------------------------------------------------------------------
// 6-way QKV GEMM: SA (q,k,v from h) + CA (q from h; k,v from enc), N=6144.
// ---------------------------------------------------------------------------
__global__ __launch_bounds__(512) void gemm128_qkv6(
    const unsigned short* __restrict__ hA,
    const unsigned short* __restrict__ encA,
    const unsigned short* __restrict__ swq,
    const unsigned short* __restrict__ cwq,
    const float* __restrict__ sb, const float* __restrict__ cb,
    unsigned short* __restrict__ q1, unsigned short* __restrict__ k1,
    unsigned short* __restrict__ v1,
    unsigned short* __restrict__ q2, unsigned short* __restrict__ k2,
    unsigned short* __restrict__ v2,
    int M, int K)
{
    __shared__ unsigned short As[3][128][64];
    __shared__ unsigned short Bs[3][128][64];

    const int row0 = blockIdx.x * 128;
    const int col0 = blockIdx.y * 128;     // 0..6143, never straddles 1024
    const int sec = col0 >> 10;            // 0..5
    const unsigned short* __restrict__ A = (sec <= 3) ? hA : encA;
    const unsigned short* __restrict__ BT =
        (sec < 3) ? swq + (size_t)col0 * K : cwq + (size_t)(col0 - 3072) * K;
    const float* __restrict__ bias = (sec < 3) ? sb + col0 : cb + (col0 - 3072);

    const int t = threadIdx.x;
    const int w = t >> 6;
    const int lane = t & 63;
    const int quad = lane >> 4;
    const int cm = lane & 15;
    const int wrow = (w >> 2) * 64;
    const int wcol = (w & 3) * 32;

    f32x4 acc[4][2] = {};
    gemm128_core(A + (size_t)row0 * K, BT, K, 0, K, As, Bs, acc);

    unsigned short* dst = sec == 0 ? q1 : sec == 1 ? k1 : sec == 2 ? v1
                        : sec == 3 ? q2 : sec == 4 ? k2 : v2;
    const int cbase = col0 & 1023;

#pragma unroll
    for (int j = 0; j < 2; ++j) {
        float bb = bias[wcol + 16 * j + cm];
        int coll = cbase + wcol + 16 * j + cm;
#pragma unroll
        for (int i = 0; i < 4; ++i) {
#pragma unroll
            for (int r = 0; r < 4; ++r) {
                int row = row0 + wrow + 16 * i + quad * 4 + r;
                dst[(size_t)row * HDIM + coll] = f2bf(acc[i][j][r] + bb);
            }
        }
    }
}

// ---------------------------------------------------------------------------
// Batched (z=2) out-projection: z=0: C0=A0@B0^T+b0; z=1: C1=A1@B1^T+b1. f32.
// ---------------------------------------------------------------------------
__global__ __launch_bounds__(512) void gemm128_out2(
    const unsigned short* __restrict__ A0, const unsigned short* __restrict__ B0,
    const float* __restrict__ b0, float* __restrict__ C0,
    const unsigned short* __restrict__ A1, const unsigned short* __restrict__ B1,
    const float* __restrict__ b1, float* __restrict__ C1,
    int M, int N, int K)
{
    __shared__ unsigned short As[3][128][64];
    __shared__ unsigned short Bs[3][128][64];

    const int z = blockIdx.z;
    const unsigned short* __restrict__ A  = z ? A1 : A0;
    const unsigned short* __restrict__ BT = z ? B1 : B0;
    const float* __restrict__ bias = z ? b1 : b0;
    float* __restrict__ Cv = z ? C1 : C0;

    const int row0 = blockIdx.x * 128;
    const int col0 = blockIdx.y * 128;
    const int t = threadIdx.x;
    const int w = t >> 6;
    const int lane = t & 63;
    const int quad = lane >> 4;
    const int cm = lane & 15;
    const int wrow = (w >> 2) * 64;
    const int wcol = (w & 3) * 32;

    f32x4 acc[4][2] = {};
    gemm128_core(A + (size_t)row0 * K, BT + (size_t)col0 * K, K, 0, K, As, Bs, acc);

#pragma unroll
    for (int j = 0; j < 2; ++j) {
        int col = col0 + wcol + 16 * j + cm;
        float bb = bias[col];
#pragma unroll
        for (int i = 0; i < 4; ++i) {
#pragma unroll
            for (int r = 0; r < 4; ++r) {
                int row = row0 + wrow + 16 * i + quad * 4 + r;
                Cv[(size_t)row * N + col] = acc[i][j][r] + bb;
            }
        }
    }
}

// ---------------------------------------------------------------------------
// Split-K2 GEMM: z=0 computes k in [0,Kper) + bias -> C0; z=1 computes
// [Kper, 2*Kper) -> C1. f32 partials; combined in ln3.
// ---------------------------------------------------------------------------
__global__ __launch_bounds__(512) void gemm128_sk2(
    const unsigned short* __restrict__ A,
    const unsigned short* __restrict__ BT,
    const float* __restrict__ bias,
    float* __restrict__ C0, float* __restrict__ C1,
    int M, int N, int K, int Kper)
{
    __shared__ unsigned short As[3][128][64];
    __shared__ unsigned short Bs[3][128][64];

    const int z = blockIdx.z;
    const int kbeg = z * Kper;
    const int row0 = blockIdx.x * 128;
    const int col0 = blockIdx.y * 128;
    const int t = threadIdx.x;
    const int w = t >> 6;
    const int lane = t & 63;
    const int quad = lane >> 4;
    const int cm = lane & 15;
    const int wrow = (w >> 2) * 64;
    const int wcol = (w & 3) * 32;

    f32x4 acc[4][2] = {};
    gemm128_core(A + (size_t)row0 * K, BT + (size_t)col0 * K, K,
                 kbeg, kbeg + Kper, As, Bs, acc);

    float* __restrict__ Cv = z ? C1 : C0;
#pragma unroll
    for (int j = 0; j < 2; ++j) {
        int col = col0 + wcol + 16 * j + cm;
        float bb = z ? 0.0f : bias[col];
#pragma unroll
        for (int i = 0; i < 4; ++i) {
#pragma unroll
            for (int r = 0; r < 4; ++r) {
                int row = row0 + wrow + 16 * i + quad * 4 + r;
                Cv[(size_t)row * N + col] = acc[i][j][r] + bb;
            }
        }
    }
}

// ---------------------------------------------------------------------------
// Flash attention, SA+CA merged: grid (S/64, NH, 2*B).
// ---------------------------------------------------------------------------
__global__ __launch_bounds__(256) void flash_attn(
    const unsigned short* __restrict__ q1, const unsigned short* __restrict__ k1,
    const unsigned short* __restrict__ v1,
    const unsigned short* __restrict__ q2, const unsigned short* __restrict__ k2,
    const unsigned short* __restrict__ v2,
    const int* __restrict__ mask1, const int* __restrict__ mask2,
    unsigned short* __restrict__ ctx1, unsigned short* __restrict__ ctx2)
{
    __shared__ unsigned short Qs[64][64];
    __shared__ unsigned short Ks[64][64];
    __shared__ unsigned short Vs[64][72];
    __shared__ unsigned short Ps[4][16][72];

    const int t = threadIdx.x;
    const int w = t >> 6;
    const int lane = t & 63;
    const int quad = lane >> 4;
    const int cm = lane & 15;
    const int sw = cm & 7;

    const int q0 = blockIdx.x * 64;
    const int h = blockIdx.y;
    const int zz = blockIdx.z;
    const int b = zz & (BDIM - 1);
    const int which = zz >> 2;
    const unsigned short* __restrict__ q = which ? q2 : q1;
    const unsigned short* __restrict__ k = which ? k2 : k1;
    const unsigned short* __restrict__ v = which ? v2 : v1;
    const int* __restrict__ mask = which ? mask2 : mask1;
    unsigned short* __restrict__ ctx = which ? ctx2 : ctx1;

    const size_t rowbase = (size_t)b * SDIM;
    const int hoff = h * DHEAD;

#pragma unroll
    for (int l = 0; l < 2; ++l) {
        int idx = t + l * 256;
        int r = idx >> 3;
        int c = idx & 7;
        *(uint4*)&Qs[r][((c ^ (r & 7)) * 8)] =
            *(const uint4*)(q + (rowbase + q0 + r) * HDIM + hoff + c * 8);
    }

    float m_prev[4] = {-1e30f, -1e30f, -1e30f, -1e30f};
    float l_sum[4] = {0.0f, 0.0f, 0.0f, 0.0f};
    f32x4 oacc[4] = {};

    for (int j0 = 0; j0 < SDIM; j0 += 64) {
        __syncthreads();
#pragma unroll
        for (int l = 0; l < 2; ++l) {
            int idx = t + l * 256;
            int r = idx >> 3;
            int c = idx & 7;
            *(uint4*)&Ks[r][((c ^ (r & 7)) * 8)] =
                *(const uint4*)(k + (rowbase + j0 + r) * HDIM + hoff + c * 8);
        }
#pragma unroll
        for (int l = 0; l < 4; ++l) {
            int idx = t + l * 256;
            int jj = idx >> 4;
            int d0 = (idx & 15) * 4;
            ushort4 vv = *(const ushort4*)(v + (rowbase + j0 + jj) * HDIM + hoff + d0);
            Vs[d0 + 0][jj] = vv.x;
            Vs[d0 + 1][jj] = vv.y;
            Vs[d0 + 2][jj] = vv.z;
            Vs[d0 + 3][jj] = vv.w;
        }
        __syncthreads();

        f32x4 sacc[4] = {};
#pragma unroll
        for (int kk = 0; kk < 64; kk += 32) {
            const int cc = kk >> 3;
            bf16x8 av = *(const bf16x8*)&Qs[w * 16 + cm][((cc + quad) ^ sw) * 8];
#pragma unroll
            for (int j2 = 0; j2 < 4; ++j2) {
                bf16x8 bv = *(const bf16x8*)&Ks[j2 * 16 + cm][((cc + quad) ^ sw) * 8];
                sacc[j2] = __builtin_amdgcn_mfma_f32_16x16x32_bf16(av, bv, sacc[j2], 0, 0, 0);
            }
        }

        float madd[4];
#pragma unroll
        for (int j2 = 0; j2 < 4; ++j2)
            madd[j2] = (1.0f - (float)mask[b * SDIM + j0 + j2 * 16 + cm]) * -10000.0f;

#pragma unroll
        for (int r = 0; r < 4; ++r) {
            float s0 = sacc[0][r] * 0.125f + madd[0];
            float s1 = sacc[1][r] * 0.125f + madd[1];
            float s2 = sacc[2][r] * 0.125f + madd[2];
            float s3 = sacc[3][r] * 0.125f + madd[3];
            float rm = fmaxf(fmaxf(s0, s1), fmaxf(s2, s3));
#pragma unroll
            for (int mo = 1; mo < 16; mo <<= 1)
                rm = fmaxf(rm, __shfl_xor(rm, mo, 64));
            float new_m = fmaxf(m_prev[r], rm);
            float alpha = __expf(m_prev[r] - new_m);
            m_prev[r] = new_m;
            float p0 = __expf(s0 - new_m);
            float p1 = __expf(s1 - new_m);
            float p2 = __expf(s2 - new_m);
            float p3 = __expf(s3 - new_m);
            float rs = p0 + p1 + p2 + p3;
#pragma unroll
            for (int mo = 1; mo < 16; mo <<= 1)
                rs += __shfl_xor(rs, mo, 64);
            l_sum[r] = l_sum[r] * alpha + rs;
#pragma unroll
            for (int d2 = 0; d2 < 4; ++d2)
                oacc[d2][r] *= alpha;
            int prow = quad * 4 + r;
            Ps[w][prow][0 * 16 + cm] = f2bf(p0);
            Ps[w][prow][1 * 16 + cm] = f2bf(p1);
            Ps[w][prow][2 * 16 + cm] = f2bf(p2);
            Ps[w][prow][3 * 16 + cm] = f2bf(p3);
        }

#pragma unroll
        for (int kk = 0; kk < 64; kk += 32) {
            bf16x8 pa = *(const bf16x8*)&Ps[w][cm][kk + quad * 8];
#pragma unroll
            for (int d2 = 0; d2 < 4; ++d2) {
                bf16x8 bv = *(const bf16x8*)&Vs[d2 * 16 + cm][kk + quad * 8];
                oacc[d2] = __builtin_amdgcn_mfma_f32_16x16x32_bf16(pa, bv, oacc[d2], 0, 0, 0);
            }
        }
    }

#pragma unroll
    for (int r = 0; r < 4; ++r) {
        float inv = 1.0f / l_sum[r];
        int row = q0 + w * 16 + quad * 4 + r;
#pragma unroll
        for (int d2 = 0; d2 < 4; ++d2) {
            ctx[(rowbase + row) * HDIM + hoff + d2 * 16 + cm] = f2bf(oacc[d2][r] * inv);
        }
    }
}

// ---------------------------------------------------------------------------
// Fused weight convert + transpose for ONE layer (7 matrices, 4352 tiles).
// ---------------------------------------------------------------------------
__global__ __launch_bounds__(256) void convtrans_all(
    const float* __restrict__ sqkv, const float* __restrict__ sout,
    const float* __restrict__ cqkv, const float* __restrict__ cout,
    const float* __restrict__ o1w,  const float* __restrict__ ffnw,
    const float* __restrict__ o2w,
    unsigned short* __restrict__ dq,  unsigned short* __restrict__ dso,
    unsigned short* __restrict__ dcq, unsigned short* __restrict__ dco,
    unsigned short* __restrict__ do1, unsigned short* __restrict__ dffn,
    unsigned short* __restrict__ do2)
{
    __shared__ unsigned short tile[64][72];
    const int bid = blockIdx.x;
    const float* src;
    unsigned short* dst;
    int K, N, tt;
    if (bid < 2304) {
        int m = bid >> 8;
        tt = bid & 255;
        K = HDIM; N = HDIM;
        if (m < 3)      { src = sqkv + (size_t)m * HSQ;       dst = dq  + (size_t)m * HSQ; }
        else if (m < 6) { src = cqkv + (size_t)(m - 3) * HSQ; dst = dcq + (size_t)(m - 3) * HSQ; }
        else if (m == 6){ src = sout; dst = dso; }
        else if (m == 7){ src = cout; dst = dco; }
        else            { src = o1w;  dst = do1; }
    } else if (bid < 3328) {
        tt = bid - 2304; K = HDIM; N = FDIM; src = ffnw; dst = dffn;
    } else {
        tt = bid - 3328; K = FDIM; N = HDIM; src = o2w; dst = do2;
    }
    const int tn = N >> 6;
    const int n0 = (tt % tn) * 64;
    const int k0 = (tt / tn) * 64;
    const int t = threadIdx.x;
#pragma unroll
    for (int l = 0; l < 4; ++l) {
        int idx = t + l * 256;
        int kk = idx >> 4;
        int nn = (idx & 15) * 4;
        float4 v = *(const float4*)(src + (size_t)(k0 + kk) * N + n0 + nn);
        tile[nn + 0][kk] = f2bf(v.x);
        tile[nn + 1][kk] = f2bf(v.y);
        tile[nn + 2][kk] = f2bf(v.z);
        tile[nn + 3][kk] = f2bf(v.w);
    }
    __syncthreads();
#pragma unroll
    for (int l = 0; l < 2; ++l) {
        int c = t + l * 256;
        int nn = c >> 3;
        int kk = (c & 7) * 8;
        *(uint4*)(dst + (size_t)(n0 + nn) * K + k0 + kk) = *(const uint4*)&tile[nn][kk];
    }
}

// ---------------------------------------------------------------------------
// LN variants. ln2: z=2 batched LN(x + resid). ln3: LN(xa + xb + resid)
// (combines split-K partials, no extra pass).
// ---------------------------------------------------------------------------
__global__ __launch_bounds__(256) void ln2_kernel(
    const float* __restrict__ xa, const float* __restrict__ xb,
    const unsigned short* __restrict__ resid,
    const float* __restrict__ lna, const float* __restrict__ lnb,
    unsigned short* __restrict__ outa, unsigned short* __restrict__ outb)
{
    const int row = blockIdx.x;
    const int z2 = blockIdx.y;
    const float* x = z2 ? xb : xa;
    const float* ln = z2 ? lnb : lna;
    unsigned short* out = z2 ? outb : outa;

    const float* xr = x + (size_t)row * HDIM;
    const unsigned short* rr = resid + (size_t)row * HDIM;
    const int t = threadIdx.x;
    __shared__ float red[4];

    float4 xv = ((const float4*)xr)[t];
    ushort4 rv = ((const ushort4*)rr)[t];
    float z[4];
    z[0] = xv.x + bf2f(rv.x);
    z[1] = xv.y + bf2f(rv.y);
    z[2] = xv.z + bf2f(rv.z);
    z[3] = xv.w + bf2f(rv.w);
    float s = z[0] + z[1] + z[2] + z[3];
#pragma unroll
    for (int off = 32; off > 0; off >>= 1) s += __shfl_down(s, off, 64);
    if ((t & 63) == 0) red[t >> 6] = s;
    __syncthreads();
    s = red[0] + red[1] + red[2] + red[3];
    float mean = s * (1.0f / (float)HDIM);

    float vs = 0.0f;
#pragma unroll
    for (int i = 0; i < 4; ++i) { float d = z[i] - mean; vs += d * d; }
#pragma unroll
    for (int off = 32; off > 0; off >>= 1) vs += __shfl_down(vs, off, 64);
    __syncthreads();
    if ((t & 63) == 0) red[t >> 6] = vs;
    __syncthreads();
    vs = red[0] + red[1] + red[2] + red[3];
    float inv = rsqrtf(vs * (1.0f / (float)HDIM) + 1e-12f);

    const float* g = ln + 4 * t;
    const float* bb = ln + HDIM + 4 * t;
    ushort4 o;
    o.x = f2bf((z[0] - mean) * inv * g[0] + bb[0]);
    o.y = f2bf((z[1] - mean) * inv * g[1] + bb[1]);
    o.z = f2bf((z[2] - mean) * inv * g[2] + bb[2]);
    o.w = f2bf((z[3] - mean) * inv * g[3] + bb[3]);
    ((ushort4*)(out + (size_t)row * HDIM))[t] = o;
}

template<bool OUTF32>
__global__ __launch_bounds__(256) void ln3_kernel(
    const float* __restrict__ xa, const float* __restrict__ xb,
    const unsigned short* __restrict__ resid,
    const float* __restrict__ ln, void* __restrict__ out)
{
    const int row = blockIdx.x;
    const float* xar = xa + (size_t)row * HDIM;
    const float* xbr = xb + (size_t)row * HDIM;
    const unsigned short* rr = resid + (size_t)row * HDIM;
    const int t = threadIdx.x;
    __shared__ float red[4];

    float4 av = ((const float4*)xar)[t];
    float4 bv = ((const float4*)xbr)[t];
    ushort4 rv = ((const ushort4*)rr)[t];
    float z[4];
    z[0] = av.x + bv.x + bf2f(rv.x);
    z[1] = av.y + bv.y + bf2f(rv.y);
    z[2] = av.z + bv.z + bf2f(rv.z);
    z[3] = av.w + bv.w + bf2f(rv.w);
    float s = z[0] + z[1] + z[2] + z[3];
#pragma unroll
    for (int off = 32; off > 0; off >>= 1) s += __shfl_down(s, off, 64);
    if ((t & 63) == 0) red[t >> 6] = s;
    __syncthreads();
    s = red[0] + red[1] + red[2] + red[3];
    float mean = s * (1.0f / (float)HDIM);

    float vs = 0.0f;
#pragma unroll
    for (int i = 0; i < 4; ++i) { float d = z[i] - mean; vs += d * d; }
#pragma unroll
    for (int off = 32; off > 0; off >>= 1) vs += __shfl_down(vs, off, 64);
    __syncthreads();
    if ((t & 63) == 0) red[t >> 6] = vs;
    __syncthreads();
    vs = red[0] + red[1] + red[2] + red[3];
    float inv = rsqrtf(vs * (1.0f / (float)HDIM) + 1e-12f);

    const float* g = ln + 4 * t;
    const float* bb = ln + HDIM + 4 * t;
    if (OUTF32) {
        float4 o;
        o.x = (z[0] - mean) * inv * g[0] + bb[0];
        o.y = (z[1] - mean) * inv * g[1] + bb[1];
        o.z = (z[2] - mean) * inv * g[2] + bb[2];
        o.w = (z[3] - mean) * inv * g[3] + bb[3];
        ((float4*)((float*)out + (size_t)row * HDIM))[t] = o;
    } else {
        ushort4 o;
        o.x = f2bf((z[0] - mean) * inv * g[0] + bb[0]);
        o.y = f2bf((z[1] - mean) * inv * g[1] + bb[1]);
        o.z = f2bf((z[2] - mean) * inv * g[2] + bb[2]);
        o.w = f2bf((z[3] - mean) * inv * g[3] + bb[3]);
        ((ushort4*)((unsigned short*)out + (size_t)row * HDIM))[t] = o;
    }
}

__global__ __launch_bounds__(256) void cvt_bf16_kernel(
    const float* __restrict__ in, unsigned short* __restrict__ out, int n4)
{
    int i = blockIdx.x * 256 + threadIdx.x;
    if (i < n4) {
        float4 v = ((const float4*)in)[i];
        ushort4 o;
        o.x = f2bf(v.x); o.y = f2bf(v.y); o.z = f2bf(v.z); o.w = f2bf(v.w);
        ((ushort4*)out)[i] = o;
    }
}

// ---------------------------------------------------------------------------
extern "C" void kernel_launch(void* const* d_in, const int* in_sizes, int n_in,
                              void* d_out, int out_size, void* d_ws, size_t ws_size,
                              hipStream_t stream)
{
    const float* in_hidden = (const float*)d_in[0];
    const float* enc_f     = (const float*)d_in[1];
    const int* attn_mask   = (const int*)d_in[2];
    const int* enc_attn_mask = (const int*)d_in[3];
    const float* sa_qkv_w  = (const float*)d_in[4];
    const float* sa_qkv_b  = (const float*)d_in[5];
    const float* sa_out_w  = (const float*)d_in[6];
    const float* sa_out_b  = (const float*)d_in[7];
    const float* sa_ln     = (const float*)d_in[8];
    const float* ca_qkv_w  = (const float*)d_in[9];
    const float* ca_qkv_b  = (const float*)d_in[10];
    const float* ca_out_w  = (const float*)d_in[11];
    const float* ca_out_b  = (const float*)d_in[12];
    const float* ca_ln     = (const float*)d_in[13];
    const float* o1_w      = (const float*)d_in[14];
    const float* o1_b      = (const float*)d_in[15];
    const float* o1_ln     = (const float*)d_in[16];
    const float* ffn_w     = (const float*)d_in[17];
    const float* ffn_b     = (const float*)d_in[18];
    const float* o2_w      = (const float*)d_in[19];
    const float* o2_b      = (const float*)d_in[20];
    const float* o2_ln     = (const float*)d_in[21];

    const size_t MH  = (size_t)MROWS * HDIM;
    const size_t Hsq = (size_t)HDIM * HDIM;
    const size_t HF  = (size_t)HDIM * FDIM;

    char* p = (char*)d_ws;
    unsigned short* wbf = (unsigned short*)p; p += (9 * Hsq + 2 * HF) * 2;
    float* t2a    = (float*)p; p += MH * 4;
    float* t2b    = (float*)p; p += MH * 4;
    unsigned short* qb     = (unsigned short*)p; p += MH * 2;
    unsigned short* kb     = (unsigned short*)p; p += MH * 2;
    unsigned short* vb     = (unsigned short*)p; p += MH * 2;
    unsigned short* qb2    = (unsigned short*)p; p += MH * 2;
    unsigned short* kb2    = (unsigned short*)p; p += MH * 2;
    unsigned short* vb2    = (unsigned short*)p; p += MH * 2;
    unsigned short* ctx    = (unsigned short*)p; p += MH * 2;
    unsigned short* ctx2   = (unsigned short*)p; p += MH * 2;
    unsigned short* h      = (unsigned short*)p; p += MH * 2;
    unsigned short* enc_bf = (unsigned short*)p; p += MH * 2;
    unsigned short* attn1  = (unsigned short*)p; p += MH * 2;
    unsigned short* crossb = (unsigned short*)p; p += MH * 2;
    unsigned short* attn2  = (unsigned short*)p; p += MH * 2;
    unsigned short* tmp8b  = (unsigned short*)p; p += (size_t)MROWS * FDIM * 2;

    unsigned short* w_saqkv = wbf;
    unsigned short* w_saout = wbf + 3 * Hsq;
    unsigned short* w_caqkv = wbf + 4 * Hsq;
    unsigned short* w_caout = wbf + 7 * Hsq;
    unsigned short* w_o1    = wbf + 8 * Hsq;
    unsigned short* w_ffn   = wbf + 9 * Hsq;
    unsigned short* w_o2    = wbf + 9 * Hsq + HF;

    cvt_bf16_kernel<<<(MH / 4 + 255) / 256, 256, 0, stream>>>(in_hidden, h, MH / 4);
    cvt_bf16_kernel<<<(MH / 4 + 255) / 256, 256, 0, stream>>>(enc_f, enc_bf, MH / 4);

    for (int l = 0; l < LNUM; ++l) {
        convtrans_all<<<4352, 256, 0, stream>>>(
            sa_qkv_w + (size_t)l * 3 * Hsq, sa_out_w + (size_t)l * Hsq,
            ca_qkv_w + (size_t)l * 3 * Hsq, ca_out_w + (size_t)l * Hsq,
            o1_w + (size_t)l * Hsq, ffn_w + (size_t)l * HF, o2_w + (size_t)l * HF,
            w_saqkv, w_saout, w_caqkv, w_caout, w_o1, w_ffn, w_o2);

        // ---- SA + CA QKV projections (N=6144, 768 blocks) ----
        gemm128_qkv6<<<dim3(MROWS / 128, 6144 / 128), 512, 0, stream>>>(
            h, enc_bf, w_saqkv, w_caqkv,
            sa_qkv_b + (size_t)l * 3 * HDIM, ca_qkv_b + (size_t)l * 3 * HDIM,
            qb, kb, vb, qb2, kb2, vb2, MROWS, HDIM);

        // ---- SA + CA flash attention ----
        flash_attn<<<dim3(SDIM / 64, NHEAD, 2 * BDIM), 256, 0, stream>>>(
            qb, kb, vb, qb2, kb2, vb2, attn_mask, enc_attn_mask, ctx, ctx2);

        // ---- SA + CA output projections (z=2, 256 blocks) ----
        gemm128_out2<<<dim3(MROWS / 128, HDIM / 128, 2), 512, 0, stream>>>(
            ctx, w_saout, sa_out_b + (size_t)l * HDIM, t2a,
            ctx2, w_caout, ca_out_b + (size_t)l * HDIM, t2b,
            MROWS, HDIM, HDIM);

        // ---- both LNs (residual = h) ----
        ln2_kernel<<<dim3(MROWS, 2), 256, 0, stream>>>(
            t2a, t2b, h, sa_ln + (size_t)l * 2 * HDIM, ca_ln + (size_t)l * 2 * HDIM,
            attn1, crossb);

        // ---- output_1: split-K2 (256 blocks), combine in ln3 ----
        gemm128_sk2<<<dim3(MROWS / 128, HDIM / 128, 2), 512, 0, stream>>>(
            attn1, w_o1, o1_b + (size_t)l * HDIM, t2a, t2b, MROWS, HDIM, HDIM, HDIM / 2);
        ln3_kernel<false><<<MROWS, 256, 0, stream>>>(
            t2a, t2b, crossb, o1_ln + (size_t)l * 2 * HDIM, attn2);

        // ---- FFN ----
        gemm128<true, true><<<dim3(MROWS / 128, FDIM / 128), 512, 0, stream>>>(
            attn2, w_ffn, ffn_b + (size_t)l * FDIM, tmp8b, MROWS, FDIM, HDIM);
        gemm128_sk2<<<dim3(MROWS / 128, HDIM / 128, 2), 512, 0, stream>>>(
            tmp8b, w_o2, o2_b + (size_t)l * HDIM, t2a, t2b, MROWS, HDIM, FDIM, FDIM / 2);
        if (l == LNUM - 1)
            ln3_kernel<true><<<MROWS, 256, 0, stream>>>(
                t2a, t2b, attn2, o2_ln + (size_t)l * 2 * HDIM, (float*)d_out);
        else
            ln3_kernel<false><<<MROWS, 256, 0, stream>>>(
                t2a, t2b, attn2, o2_ln + (size_t)l * 2 * HDIM, h);
    }
}